// Round 2
// baseline (3095.238 us; speedup 1.0000x reference)
//
#include <hip/hip_runtime.h>
#include <hip/hip_bf16.h>
#include <math.h>

// Problem constants (from reference)
#define F_IN   128
#define HID    128
#define HEADS  4
#define HC1    (HEADS*HID)   // 512
#define CLASSES 2
#define NEG_SLOPE 0.2f

// ---------------------------------------------------------------------------
// utility: float atomic max via int/uint trick
// ---------------------------------------------------------------------------
__device__ __forceinline__ void atomicMaxFloat(float* addr, float value) {
    if (value >= 0.0f) {
        atomicMax((int*)addr, __float_as_int(value));
    } else {
        atomicMin((unsigned int*)addr, __float_as_uint(value));
    }
}

__global__ void fill_kernel(float* __restrict__ p, float v, int n) {
    int i = blockIdx.x * blockDim.x + threadIdx.x;
    int stride = gridDim.x * blockDim.x;
    for (; i < n; i += stride) p[i] = v;
}

// ---------------------------------------------------------------------------
// Tiled fp32 GEMM: C[M,N] = A[M,K] @ B[K,N] (+bias) (+elu)
// BM=BN=64, BK=16, 256 threads, 4x4 per thread.
// ---------------------------------------------------------------------------
template<int ACT>   // 0 = none, 1 = elu
__global__ __launch_bounds__(256) void gemm_kernel(
    const float* __restrict__ A, const float* __restrict__ B,
    const float* __restrict__ bias, float* __restrict__ C,
    int M, int K, int N)
{
    const int tx = threadIdx.x & 15;
    const int ty = threadIdx.x >> 4;
    const int row0 = blockIdx.y * 64;
    const int col0 = blockIdx.x * 64;

    __shared__ float As[16][68];  // As[k][m] (A transposed in LDS)
    __shared__ float Bs[16][68];  // Bs[k][n]

    float acc[4][4] = {};

    for (int k0 = 0; k0 < K; k0 += 16) {
        // load A tile 64x16 -> As[k][m]
        #pragma unroll
        for (int idx = threadIdx.x; idx < 64 * 16; idx += 256) {
            int r = idx >> 4, c = idx & 15;
            int gr = row0 + r;
            float v = (gr < M) ? A[(size_t)gr * K + (k0 + c)] : 0.0f;
            As[c][r] = v;
        }
        // load B tile 16x64 -> Bs[k][n]
        #pragma unroll
        for (int idx = threadIdx.x; idx < 16 * 64; idx += 256) {
            int r = idx >> 6, c = idx & 63;
            Bs[r][c] = B[(size_t)(k0 + r) * N + (col0 + c)];
        }
        __syncthreads();
        #pragma unroll
        for (int k = 0; k < 16; ++k) {
            float a[4], b[4];
            #pragma unroll
            for (int i = 0; i < 4; ++i) a[i] = As[k][ty * 4 + i];
            #pragma unroll
            for (int j = 0; j < 4; ++j) b[j] = Bs[k][tx * 4 + j];
            #pragma unroll
            for (int i = 0; i < 4; ++i)
                #pragma unroll
                for (int j = 0; j < 4; ++j)
                    acc[i][j] += a[i] * b[j];
        }
        __syncthreads();
    }

    #pragma unroll
    for (int i = 0; i < 4; ++i) {
        int r = row0 + ty * 4 + i;
        if (r >= M) continue;
        #pragma unroll
        for (int j = 0; j < 4; ++j) {
            int c = col0 + tx * 4 + j;
            float v = acc[i][j] + (bias ? bias[c] : 0.0f);
            if (ACT == 1) v = (v > 0.0f) ? v : expm1f(v);
            C[(size_t)r * N + c] = v;
        }
    }
}

// ---------------------------------------------------------------------------
// edge index fetch with defensive clamp (turns any bad index into a wrong
// answer instead of a GPU memory fault — diagnosable)
// ---------------------------------------------------------------------------
__device__ __forceinline__ void edge_nodes(const int* __restrict__ src_arr,
                                           const int* __restrict__ dst_arr,
                                           int e, int E, int N, int& s, int& d) {
    if (e < E) { s = src_arr[e]; d = dst_arr[e]; } else { s = d = e - E; }
    if ((unsigned)s >= (unsigned)N) s = 0;
    if ((unsigned)d >= (unsigned)N) d = 0;
}

// ---------------------------------------------------------------------------
// Layer 1 edge kernels (H=4, C=128; node feature rows are 512 floats)
// ---------------------------------------------------------------------------
__global__ __launch_bounds__(256) void edge_logits1_kernel(
    const float* __restrict__ xl, const float* __restrict__ xr,
    const int* __restrict__ src_arr, const int* __restrict__ dst_arr,
    int E, int Etot, int N, const float* __restrict__ att,
    float* __restrict__ logits, float* __restrict__ mmax)
{
    int e = blockIdx.x * 4 + (threadIdx.x >> 6);
    if (e >= Etot) return;
    int lane = threadIdx.x & 63;
    int s, d;
    edge_nodes(src_arr, dst_arr, e, E, N, s, d);
    const float* xls = xl + (size_t)s * HC1;
    const float* xrd = xr + (size_t)d * HC1;
    #pragma unroll
    for (int h = 0; h < HEADS; ++h) {
        int b = h * 128;
        float v0 = xls[b + lane]      + xrd[b + lane];
        float v1 = xls[b + 64 + lane] + xrd[b + 64 + lane];
        v0 = (v0 > 0.0f) ? v0 : NEG_SLOPE * v0;
        v1 = (v1 > 0.0f) ? v1 : NEG_SLOPE * v1;
        float acc = v0 * att[b + lane] + v1 * att[b + 64 + lane];
        #pragma unroll
        for (int off = 32; off; off >>= 1) acc += __shfl_xor(acc, off);
        if (lane == 0) {
            logits[(size_t)e * HEADS + h] = acc;
            atomicMaxFloat(&mmax[d * HEADS + h], acc);
        }
    }
}

__global__ void edge_exp1_kernel(
    float* __restrict__ logits, const float* __restrict__ mmax,
    float* __restrict__ denom, const int* __restrict__ dst_arr,
    int E, int Etot, int N)
{
    int t = blockIdx.x * blockDim.x + threadIdx.x;
    if (t >= Etot * HEADS) return;
    int e = t >> 2, h = t & 3;
    int d = (e < E) ? dst_arr[e] : (e - E);
    if ((unsigned)d >= (unsigned)N) d = 0;
    float p = __expf(logits[t] - mmax[d * HEADS + h]);
    logits[t] = p;
    atomicAdd(&denom[d * HEADS + h], p);
}

__global__ __launch_bounds__(256) void aggregate1_kernel(
    const float* __restrict__ xl, const float* __restrict__ p,
    const float* __restrict__ denom,
    const int* __restrict__ src_arr, const int* __restrict__ dst_arr,
    int E, int Etot, int N, float* __restrict__ out)
{
    int e = blockIdx.x * 4 + (threadIdx.x >> 6);
    if (e >= Etot) return;
    int lane = threadIdx.x & 63;
    int s, d;
    edge_nodes(src_arr, dst_arr, e, E, N, s, d);
    float alpha[HEADS];
    #pragma unroll
    for (int h = 0; h < HEADS; ++h)
        alpha[h] = p[(size_t)e * HEADS + h] / (denom[d * HEADS + h] + 1e-16f);
    const float* xls = xl + (size_t)s * HC1;
    float* od = out + (size_t)d * HC1;
    #pragma unroll
    for (int j = 0; j < 8; ++j) {
        int i = j * 64 + lane;
        atomicAdd(&od[i], alpha[j >> 1] * xls[i]);
    }
}

// ---------------------------------------------------------------------------
// Layer 2 edge kernels (H=1, C=128)
// ---------------------------------------------------------------------------
__global__ __launch_bounds__(256) void edge_logits2_kernel(
    const float* __restrict__ xl, const float* __restrict__ xr,
    const int* __restrict__ src_arr, const int* __restrict__ dst_arr,
    int E, int Etot, int N, const float* __restrict__ att,
    float* __restrict__ logits, float* __restrict__ mmax)
{
    int e = blockIdx.x * 4 + (threadIdx.x >> 6);
    if (e >= Etot) return;
    int lane = threadIdx.x & 63;
    int s, d;
    edge_nodes(src_arr, dst_arr, e, E, N, s, d);
    const float* xls = xl + (size_t)s * HID;
    const float* xrd = xr + (size_t)d * HID;
    float v0 = xls[lane]      + xrd[lane];
    float v1 = xls[64 + lane] + xrd[64 + lane];
    v0 = (v0 > 0.0f) ? v0 : NEG_SLOPE * v0;
    v1 = (v1 > 0.0f) ? v1 : NEG_SLOPE * v1;
    float acc = v0 * att[lane] + v1 * att[64 + lane];
    #pragma unroll
    for (int off = 32; off; off >>= 1) acc += __shfl_xor(acc, off);
    if (lane == 0) {
        logits[e] = acc;
        atomicMaxFloat(&mmax[d], acc);
    }
}

__global__ void edge_exp2_kernel(
    float* __restrict__ logits, const float* __restrict__ mmax,
    float* __restrict__ denom, const int* __restrict__ dst_arr,
    int E, int Etot, int N)
{
    int e = blockIdx.x * blockDim.x + threadIdx.x;
    if (e >= Etot) return;
    int d = (e < E) ? dst_arr[e] : (e - E);
    if ((unsigned)d >= (unsigned)N) d = 0;
    float p = __expf(logits[e] - mmax[d]);
    logits[e] = p;
    atomicAdd(&denom[d], p);
}

__global__ __launch_bounds__(256) void aggregate2_kernel(
    const float* __restrict__ xl, const float* __restrict__ p,
    const float* __restrict__ denom,
    const int* __restrict__ src_arr, const int* __restrict__ dst_arr,
    int E, int Etot, int N, float* __restrict__ out)
{
    int e = blockIdx.x * 4 + (threadIdx.x >> 6);
    if (e >= Etot) return;
    int lane = threadIdx.x & 63;
    int s, d;
    edge_nodes(src_arr, dst_arr, e, E, N, s, d);
    float alpha = p[e] / (denom[d] + 1e-16f);
    const float* xls = xl + (size_t)s * HID;
    float* od = out + (size_t)d * HID;
    #pragma unroll
    for (int j = 0; j < 2; ++j) {
        int i = j * 64 + lane;
        atomicAdd(&od[i], alpha * xls[i]);
    }
}

// ---------------------------------------------------------------------------
// elementwise: x = elu(x + bias[i % nb])
// ---------------------------------------------------------------------------
__global__ void bias_elu_kernel(float* __restrict__ x, const float* __restrict__ bias,
                                int total, int nb)
{
    int i = blockIdx.x * blockDim.x + threadIdx.x;
    int stride = gridDim.x * blockDim.x;
    for (; i < total; i += stride) {
        float v = x[i] + bias[i % nb];
        x[i] = (v > 0.0f) ? v : expm1f(v);
    }
}

// ---------------------------------------------------------------------------
// final: out = log_softmax(h2 @ w_out + b_out), CLASSES=2. One wave per node.
// ---------------------------------------------------------------------------
__global__ __launch_bounds__(256) void final_kernel(
    const float* __restrict__ h2, const float* __restrict__ w_out,
    const float* __restrict__ b_out, float* __restrict__ out, int Nn)
{
    int n = blockIdx.x * 4 + (threadIdx.x >> 6);
    if (n >= Nn) return;
    int lane = threadIdx.x & 63;
    const float* hr = h2 + (size_t)n * HID;
    float a0 = 0.0f, a1 = 0.0f;
    #pragma unroll
    for (int j = 0; j < 2; ++j) {
        int c = j * 64 + lane;
        float hv = hr[c];
        a0 += hv * w_out[c * CLASSES + 0];
        a1 += hv * w_out[c * CLASSES + 1];
    }
    #pragma unroll
    for (int off = 32; off; off >>= 1) {
        a0 += __shfl_xor(a0, off);
        a1 += __shfl_xor(a1, off);
    }
    if (lane == 0) {
        float z0 = a0 + b_out[0];
        float z1 = a1 + b_out[1];
        float m = fmaxf(z0, z1);
        float lse = m + logf(__expf(z0 - m) + __expf(z1 - m));
        out[(size_t)n * CLASSES + 0] = z0 - lse;
        out[(size_t)n * CLASSES + 1] = z1 - lse;
    }
}

// ---------------------------------------------------------------------------
// launch — liveness-overlaid workspace, peak ≈ 245.6 MB
// ---------------------------------------------------------------------------
extern "C" void kernel_launch(void* const* d_in, const int* in_sizes, int n_in,
                              void* d_out, int out_size, void* d_ws, size_t ws_size,
                              hipStream_t stream)
{
    const float* x     = (const float*)d_in[0];
    const int*   eidx  = (const int*)d_in[1];
    const float* w_in  = (const float*)d_in[2];
    const float* b_in  = (const float*)d_in[3];
    const float* wl1   = (const float*)d_in[4];
    const float* wr1   = (const float*)d_in[5];
    const float* att1  = (const float*)d_in[6];
    const float* b1    = (const float*)d_in[7];
    const float* wl2   = (const float*)d_in[8];
    const float* wr2   = (const float*)d_in[9];
    const float* att2  = (const float*)d_in[10];
    const float* b2    = (const float*)d_in[11];
    const float* w_out = (const float*)d_in[12];
    const float* b_out = (const float*)d_in[13];
    float* out = (float*)d_out;

    const int N = in_sizes[0] / F_IN;      // 50000
    const int E = in_sizes[1] / 2;         // 800000
    const int Etot = E + N;                // with self loops
    const int* src_arr = eidx;
    const int* dst_arr = eidx + E;

    // ---- workspace layout with liveness overlays ----
    // R1 [N*HC1 f32]: xl1 (L1 gemm -> aggregate1), then xl2 | xr2 (each N*HID)
    // R2 [N*HC1 f32]: xr1 (L1 gemm -> logits1), then out1 (aggregate1 -> L2 gemms)
    // R3 [N*HID f32]: h0 (input gemm -> L1 gemms), then out2
    // R4 [Etot*HEADS f32]: logits1 / logits2
    // R5,R6 [N*HEADS f32]: m, d
    size_t off = 0;
    auto alloc = [&](size_t bytes) -> float* {
        float* ptr = (float*)((char*)d_ws + off);
        off += (bytes + 255) & ~(size_t)255;
        return ptr;
    };
    float* R1 = alloc((size_t)N * HC1 * 4);
    float* R2 = alloc((size_t)N * HC1 * 4);
    float* R3 = alloc((size_t)N * HID * 4);
    float* R4 = alloc((size_t)Etot * HEADS * 4);
    float* R5 = alloc((size_t)N * HEADS * 4);
    float* R6 = alloc((size_t)N * HEADS * 4);

    float* h0      = R3;
    float* xl1     = R1;
    float* xr1     = R2;
    float* out1    = R2;               // overlays xr1 (dead after logits1)
    float* logits1 = R4;
    float* m1      = R5;
    float* d1      = R6;

    float* xl2     = R1;               // overlays xl1 (dead after aggregate1)
    float* xr2     = R1 + (size_t)N * HID;
    float* out2    = R3;               // overlays h0 (dead after L1 gemms)
    float* logits2 = R4;
    float* m2      = R5;
    float* d2      = R6;

    const float NEG_INF = -__builtin_huge_valf();
    dim3 blk(256);

    // ---- input transform: h0 = elu(x @ w_in + b_in) ----
    {
        dim3 grid((HID + 63) / 64, (N + 63) / 64);
        hipLaunchKernelGGL((gemm_kernel<1>), grid, blk, 0, stream, x, w_in, b_in, h0, N, F_IN, HID);
    }
    // ---- layer 1 transforms ----
    {
        dim3 grid((HC1 + 63) / 64, (N + 63) / 64);
        hipLaunchKernelGGL((gemm_kernel<0>), grid, blk, 0, stream, h0, wl1, nullptr, xl1, N, HID, HC1);
        hipLaunchKernelGGL((gemm_kernel<0>), grid, blk, 0, stream, h0, wr1, nullptr, xr1, N, HID, HC1);
    }
    // ---- init segment buffers ----
    {
        int nm = N * HEADS;
        hipLaunchKernelGGL(fill_kernel, dim3(512), blk, 0, stream, m1, NEG_INF, nm);
        hipLaunchKernelGGL(fill_kernel, dim3(512), blk, 0, stream, d1, 0.0f, nm);
    }
    // ---- layer 1 edge phase ----
    {
        dim3 grid((Etot + 3) / 4);
        hipLaunchKernelGGL(edge_logits1_kernel, grid, blk, 0, stream,
                           xl1, xr1, src_arr, dst_arr, E, Etot, N, att1, logits1, m1);
        dim3 gexp((Etot * HEADS + 255) / 256);
        hipLaunchKernelGGL(edge_exp1_kernel, gexp, blk, 0, stream,
                           logits1, m1, d1, dst_arr, E, Etot, N);
        // xr1 is now dead -> out1 overlays it; zero it before aggregation
        hipLaunchKernelGGL(fill_kernel, dim3(2048), blk, 0, stream, out1, 0.0f, N * HC1);
        hipLaunchKernelGGL(aggregate1_kernel, grid, blk, 0, stream,
                           xl1, logits1, d1, src_arr, dst_arr, E, Etot, N, out1);
        hipLaunchKernelGGL(bias_elu_kernel, dim3(2048), blk, 0, stream, out1, b1, N * HC1, HC1);
    }
    // ---- layer 2 transforms (xl1 dead -> R1 reused) ----
    {
        dim3 grid((HID + 63) / 64, (N + 63) / 64);
        hipLaunchKernelGGL((gemm_kernel<0>), grid, blk, 0, stream, out1, wl2, nullptr, xl2, N, HC1, HID);
        hipLaunchKernelGGL((gemm_kernel<0>), grid, blk, 0, stream, out1, wr2, nullptr, xr2, N, HC1, HID);
    }
    // ---- init segment buffers (layer 2) ----
    {
        hipLaunchKernelGGL(fill_kernel, dim3(256), blk, 0, stream, m2, NEG_INF, N);
        hipLaunchKernelGGL(fill_kernel, dim3(256), blk, 0, stream, d2, 0.0f, N);
        hipLaunchKernelGGL(fill_kernel, dim3(1024), blk, 0, stream, out2, 0.0f, N * HID);
    }
    // ---- layer 2 edge phase ----
    {
        dim3 grid((Etot + 3) / 4);
        hipLaunchKernelGGL(edge_logits2_kernel, grid, blk, 0, stream,
                           xl2, xr2, src_arr, dst_arr, E, Etot, N, att2, logits2, m2);
        dim3 gexp((Etot + 255) / 256);
        hipLaunchKernelGGL(edge_exp2_kernel, gexp, blk, 0, stream,
                           logits2, m2, d2, dst_arr, E, Etot, N);
        hipLaunchKernelGGL(aggregate2_kernel, grid, blk, 0, stream,
                           xl2, logits2, d2, src_arr, dst_arr, E, Etot, N, out2);
        hipLaunchKernelGGL(bias_elu_kernel, dim3(1024), blk, 0, stream, out2, b2, N * HID, HID);
    }
    // ---- final classifier + log_softmax ----
    {
        dim3 grid((N + 3) / 4);
        hipLaunchKernelGGL(final_kernel, grid, blk, 0, stream, out2, w_out, b_out, out, N);
    }
}

// Round 3
// 1000.657 us; speedup vs baseline: 3.0932x; 3.0932x over previous
//
#include <hip/hip_runtime.h>
#include <hip/hip_bf16.h>
#include <math.h>

// Problem constants (from reference)
#define F_IN   128
#define HID    128
#define HEADS  4
#define HC1    (HEADS*HID)   // 512
#define CLASSES 2
#define NEG_SLOPE 0.2f

#define SCAN_CHUNK 2048

// ---------------------------------------------------------------------------
// CSR build: deg histogram -> exclusive scan -> scatter src ids by dst
// ---------------------------------------------------------------------------
__global__ void zero_int_kernel(int* __restrict__ p, int n) {
    int i = blockIdx.x * blockDim.x + threadIdx.x;
    int stride = gridDim.x * blockDim.x;
    for (; i < n; i += stride) p[i] = 0;
}

__global__ void deg_kernel(const int* __restrict__ dst_arr, int* __restrict__ deg,
                           int E, int N) {
    int e = blockIdx.x * blockDim.x + threadIdx.x;
    if (e >= E) return;
    int d = dst_arr[e];
    if ((unsigned)d >= (unsigned)N) d = 0;
    atomicAdd(&deg[d], 1);
}

__global__ void scan_partial_kernel(const int* __restrict__ deg, int* __restrict__ bsum, int n) {
    __shared__ int sdata[256];
    int b = blockIdx.x, t = threadIdx.x;
    int base = b * SCAN_CHUNK;
    int s = 0;
    for (int i = t; i < SCAN_CHUNK; i += 256) {
        int idx = base + i;
        s += (idx < n) ? deg[idx] : 0;
    }
    sdata[t] = s;
    __syncthreads();
    for (int off = 128; off; off >>= 1) {
        if (t < off) sdata[t] += sdata[t + off];
        __syncthreads();
    }
    if (t == 0) bsum[b] = sdata[0];
}

__global__ void scan_bsums_kernel(int* __restrict__ bsum, int nb, int* __restrict__ row, int n) {
    if (blockIdx.x == 0 && threadIdx.x == 0) {
        int acc = 0;
        for (int i = 0; i < nb; ++i) { int v = bsum[i]; bsum[i] = acc; acc += v; }
        row[n] = acc;   // total edge count
    }
}

__global__ void scan_final_kernel(const int* __restrict__ deg, const int* __restrict__ bsum,
                                  int* __restrict__ row, int* __restrict__ cursor, int n) {
    __shared__ int tsum[256];
    int b = blockIdx.x, t = threadIdx.x;
    int base = b * SCAN_CHUNK + t * 8;
    int local[8];
    int s = 0;
    #pragma unroll
    for (int k = 0; k < 8; ++k) {
        int idx = base + k;
        int v = (idx < n) ? deg[idx] : 0;
        local[k] = s;
        s += v;
    }
    tsum[t] = s;
    __syncthreads();
    for (int off = 1; off < 256; off <<= 1) {
        int v = 0;
        if (t >= off) v = tsum[t - off];
        __syncthreads();
        if (t >= off) tsum[t] += v;
        __syncthreads();
    }
    int texcl = (t == 0) ? 0 : tsum[t - 1];
    // tsum now inclusive; recompute exclusive via t-1 read done above before overwrite? safe: loop done.
    int boff = bsum[b];
    #pragma unroll
    for (int k = 0; k < 8; ++k) {
        int idx = base + k;
        if (idx < n) {
            int v = boff + texcl + local[k];
            row[idx] = v;
            cursor[idx] = v;
        }
    }
}

__global__ void scatter_kernel(const int* __restrict__ src_arr, const int* __restrict__ dst_arr,
                               int* __restrict__ cursor, int* __restrict__ src_sorted,
                               int E, int N) {
    int e = blockIdx.x * blockDim.x + threadIdx.x;
    if (e >= E) return;
    int s = src_arr[e], d = dst_arr[e];
    if ((unsigned)s >= (unsigned)N) s = 0;
    if ((unsigned)d >= (unsigned)N) d = 0;
    int pos = atomicAdd(&cursor[d], 1);
    src_sorted[pos] = s;
}

// ---------------------------------------------------------------------------
// Tiled fp32 GEMM: C[M,N] = A[M,K] @ B[K,N] (+bias) (+elu), templated output
// BM=BN=64, BK=16, 256 threads, 4x4 per thread.
// ---------------------------------------------------------------------------
template<int ACT, typename OutT>   // ACT: 0 = none, 1 = elu
__global__ __launch_bounds__(256) void gemm_kernel(
    const float* __restrict__ A, const float* __restrict__ B,
    const float* __restrict__ bias, OutT* __restrict__ C,
    int M, int K, int N)
{
    const int tx = threadIdx.x & 15;
    const int ty = threadIdx.x >> 4;
    const int row0 = blockIdx.y * 64;
    const int col0 = blockIdx.x * 64;

    __shared__ float As[16][68];  // As[k][m]
    __shared__ float Bs[16][68];  // Bs[k][n]

    float acc[4][4] = {};

    for (int k0 = 0; k0 < K; k0 += 16) {
        #pragma unroll
        for (int idx = threadIdx.x; idx < 64 * 16; idx += 256) {
            int r = idx >> 4, c = idx & 15;
            int gr = row0 + r;
            float v = (gr < M) ? A[(size_t)gr * K + (k0 + c)] : 0.0f;
            As[c][r] = v;
        }
        #pragma unroll
        for (int idx = threadIdx.x; idx < 16 * 64; idx += 256) {
            int r = idx >> 6, c = idx & 63;
            Bs[r][c] = B[(size_t)(k0 + r) * N + (col0 + c)];
        }
        __syncthreads();
        #pragma unroll
        for (int k = 0; k < 16; ++k) {
            float a[4], b[4];
            #pragma unroll
            for (int i = 0; i < 4; ++i) a[i] = As[k][ty * 4 + i];
            #pragma unroll
            for (int j = 0; j < 4; ++j) b[j] = Bs[k][tx * 4 + j];
            #pragma unroll
            for (int i = 0; i < 4; ++i)
                #pragma unroll
                for (int j = 0; j < 4; ++j)
                    acc[i][j] += a[i] * b[j];
        }
        __syncthreads();
    }

    #pragma unroll
    for (int i = 0; i < 4; ++i) {
        int r = row0 + ty * 4 + i;
        if (r >= M) continue;
        #pragma unroll
        for (int j = 0; j < 4; ++j) {
            int c = col0 + tx * 4 + j;
            float v = acc[i][j] + (bias ? bias[c] : 0.0f);
            if (ACT == 1) v = (v > 0.0f) ? v : expm1f(v);
            C[(size_t)r * N + c] = (OutT)v;
        }
    }
}

// ---------------------------------------------------------------------------
// Fused GATv2 layer 1: one wave per dst node, CSR gather, online softmax.
// xl/xr are bf16 [N,512]. out1 = elu(agg + b1), f32 [N,512].
// Lane l owns channels [8l, 8l+8); head = l/16; per-head reduce = 16-lane group.
// ---------------------------------------------------------------------------
__global__ __launch_bounds__(256) void gatv2_l1_fused_kernel(
    const __hip_bfloat16* __restrict__ xl, const __hip_bfloat16* __restrict__ xr,
    const int* __restrict__ row, const int* __restrict__ src_sorted,
    const float* __restrict__ att, const float* __restrict__ b1,
    float* __restrict__ out1, int N)
{
    int d = blockIdx.x * 4 + (threadIdx.x >> 6);
    if (d >= N) return;
    int lane = threadIdx.x & 63;
    int cbase = lane * 8;

    // xr[d] and att for this lane's channels
    float xrd[8], attv[8];
    {
        uint4 raw = *reinterpret_cast<const uint4*>(xr + (size_t)d * HC1 + cbase);
        const unsigned* u = reinterpret_cast<const unsigned*>(&raw);
        #pragma unroll
        for (int j = 0; j < 4; ++j) {
            xrd[2 * j]     = __uint_as_float(u[j] << 16);
            xrd[2 * j + 1] = __uint_as_float(u[j] & 0xffff0000u);
        }
        #pragma unroll
        for (int k = 0; k < 8; ++k) attv[k] = att[cbase + k];
    }

    float m = -__builtin_huge_valf();
    float s = 0.0f;
    float o[8] = {};

    int rs = row[d], re = row[d + 1];

    // process self-loop first, then CSR edges
    for (int it = rs - 1; it < re; ++it) {
        int srcn = (it < rs) ? d : src_sorted[it];
        float v[8];
        uint4 raw = *reinterpret_cast<const uint4*>(xl + (size_t)srcn * HC1 + cbase);
        const unsigned* u = reinterpret_cast<const unsigned*>(&raw);
        #pragma unroll
        for (int j = 0; j < 4; ++j) {
            v[2 * j]     = __uint_as_float(u[j] << 16);
            v[2 * j + 1] = __uint_as_float(u[j] & 0xffff0000u);
        }
        float t = 0.0f;
        #pragma unroll
        for (int k = 0; k < 8; ++k) {
            float e = v[k] + xrd[k];
            e = (e > 0.0f) ? e : NEG_SLOPE * e;
            t = fmaf(e, attv[k], t);
        }
        // per-head (16-lane group) reduce
        t += __shfl_xor(t, 1);
        t += __shfl_xor(t, 2);
        t += __shfl_xor(t, 4);
        t += __shfl_xor(t, 8);
        // online softmax update (t uniform within 16-lane group)
        if (t > m) {
            float r = __expf(m - t);   // exp(-inf)=0 on first edge
            s *= r;
            #pragma unroll
            for (int k = 0; k < 8; ++k) o[k] *= r;
            m = t;
        }
        float p = __expf(t - m);
        s += p;
        #pragma unroll
        for (int k = 0; k < 8; ++k) o[k] = fmaf(p, v[k], o[k]);
    }

    float inv = 1.0f / (s + 1e-16f);
    float res[8];
    #pragma unroll
    for (int k = 0; k < 8; ++k) {
        float val = o[k] * inv + b1[cbase + k];
        res[k] = (val > 0.0f) ? val : expm1f(val);
    }
    float4* op = reinterpret_cast<float4*>(out1 + (size_t)d * HC1 + cbase);
    op[0] = make_float4(res[0], res[1], res[2], res[3]);
    op[1] = make_float4(res[4], res[5], res[6], res[7]);
}

// ---------------------------------------------------------------------------
// Fused GATv2 layer 2 (H=1) + classifier + log_softmax: one wave per node.
// xl2/xr2 f32 [N,128]. Lane l owns channels [2l, 2l+2). Writes d_out [N,2].
// ---------------------------------------------------------------------------
__global__ __launch_bounds__(256) void gatv2_l2_final_kernel(
    const float* __restrict__ xl2, const float* __restrict__ xr2,
    const int* __restrict__ row, const int* __restrict__ src_sorted,
    const float* __restrict__ att2, const float* __restrict__ b2,
    const float* __restrict__ w_out, const float* __restrict__ b_out,
    float* __restrict__ out, int N)
{
    int d = blockIdx.x * 4 + (threadIdx.x >> 6);
    if (d >= N) return;
    int lane = threadIdx.x & 63;
    int c0 = lane * 2;

    float2 xrd  = *reinterpret_cast<const float2*>(xr2 + (size_t)d * HID + c0);
    float2 attv = *reinterpret_cast<const float2*>(att2 + c0);

    float m = -__builtin_huge_valf();
    float s = 0.0f;
    float o0 = 0.0f, o1 = 0.0f;

    int rs = row[d], re = row[d + 1];
    for (int it = rs - 1; it < re; ++it) {
        int srcn = (it < rs) ? d : src_sorted[it];
        float2 v = *reinterpret_cast<const float2*>(xl2 + (size_t)srcn * HID + c0);
        float e0 = v.x + xrd.x; e0 = (e0 > 0.0f) ? e0 : NEG_SLOPE * e0;
        float e1 = v.y + xrd.y; e1 = (e1 > 0.0f) ? e1 : NEG_SLOPE * e1;
        float t = fmaf(e0, attv.x, e1 * attv.y);
        #pragma unroll
        for (int off = 32; off; off >>= 1) t += __shfl_xor(t, off);
        if (t > m) {
            float r = __expf(m - t);
            s *= r; o0 *= r; o1 *= r;
            m = t;
        }
        float p = __expf(t - m);
        s += p;
        o0 = fmaf(p, v.x, o0);
        o1 = fmaf(p, v.y, o1);
    }

    float inv = 1.0f / (s + 1e-16f);
    float h0v = o0 * inv + b2[c0];
    float h1v = o1 * inv + b2[c0 + 1];
    h0v = (h0v > 0.0f) ? h0v : expm1f(h0v);
    h1v = (h1v > 0.0f) ? h1v : expm1f(h1v);

    // classifier: logits[j] = sum_c h[c] * w_out[c*2+j]
    float a0 = fmaf(h0v, w_out[c0 * 2 + 0], h1v * w_out[(c0 + 1) * 2 + 0]);
    float a1 = fmaf(h0v, w_out[c0 * 2 + 1], h1v * w_out[(c0 + 1) * 2 + 1]);
    #pragma unroll
    for (int off = 32; off; off >>= 1) {
        a0 += __shfl_xor(a0, off);
        a1 += __shfl_xor(a1, off);
    }
    if (lane == 0) {
        float z0 = a0 + b_out[0];
        float z1 = a1 + b_out[1];
        float mx = fmaxf(z0, z1);
        float lse = mx + logf(__expf(z0 - mx) + __expf(z1 - mx));
        out[(size_t)d * CLASSES + 0] = z0 - lse;
        out[(size_t)d * CLASSES + 1] = z1 - lse;
    }
}

// ---------------------------------------------------------------------------
// launch
// ---------------------------------------------------------------------------
extern "C" void kernel_launch(void* const* d_in, const int* in_sizes, int n_in,
                              void* d_out, int out_size, void* d_ws, size_t ws_size,
                              hipStream_t stream)
{
    const float* x     = (const float*)d_in[0];
    const int*   eidx  = (const int*)d_in[1];
    const float* w_in  = (const float*)d_in[2];
    const float* b_in  = (const float*)d_in[3];
    const float* wl1   = (const float*)d_in[4];
    const float* wr1   = (const float*)d_in[5];
    const float* att1  = (const float*)d_in[6];
    const float* b1    = (const float*)d_in[7];
    const float* wl2   = (const float*)d_in[8];
    const float* wr2   = (const float*)d_in[9];
    const float* att2  = (const float*)d_in[10];
    const float* b2    = (const float*)d_in[11];
    const float* w_out = (const float*)d_in[12];
    const float* b_out = (const float*)d_in[13];
    float* out = (float*)d_out;

    const int N = in_sizes[0] / F_IN;      // 50000
    const int E = in_sizes[1] / 2;         // 800000
    const int* src_arr = eidx;
    const int* dst_arr = eidx + E;

    // ---- workspace layout ----
    size_t off = 0;
    auto alloc = [&](size_t bytes) -> char* {
        char* ptr = (char*)d_ws + off;
        off += (bytes + 255) & ~(size_t)255;
        return ptr;
    };
    int* row        = (int*)alloc((size_t)(N + 1) * 4);
    int* cursor     = (int*)alloc((size_t)N * 4);
    int* deg        = (int*)alloc((size_t)N * 4);
    int* bsum       = (int*)alloc(64 * 4);
    int* src_sorted = (int*)alloc((size_t)E * 4);
    float* h0             = (float*)alloc((size_t)N * HID * 4);   // reused as xl2
    __hip_bfloat16* xl1   = (__hip_bfloat16*)alloc((size_t)N * HC1 * 2);  // reused: first N*HID*4 bytes as xr2
    __hip_bfloat16* xr1   = (__hip_bfloat16*)alloc((size_t)N * HC1 * 2);
    float* out1           = (float*)alloc((size_t)N * HC1 * 4);
    // peak ≈ 3.7 + 25.6 + 51.2 + 51.2 + 102.4 ≈ 234 MB

    float* xl2 = h0;            // h0 dead after layer-1 gemms
    float* xr2 = (float*)xl1;   // xl1 dead after fused layer-1

    dim3 blk(256);
    const int NB_SCAN = (N + SCAN_CHUNK - 1) / SCAN_CHUNK;

    // ---- CSR build ----
    hipLaunchKernelGGL(zero_int_kernel, dim3(64), blk, 0, stream, deg, N);
    hipLaunchKernelGGL(deg_kernel, dim3((E + 255) / 256), blk, 0, stream, dst_arr, deg, E, N);
    hipLaunchKernelGGL(scan_partial_kernel, dim3(NB_SCAN), blk, 0, stream, deg, bsum, N);
    hipLaunchKernelGGL(scan_bsums_kernel, dim3(1), blk, 0, stream, bsum, NB_SCAN, row, N);
    hipLaunchKernelGGL(scan_final_kernel, dim3(NB_SCAN), blk, 0, stream, deg, bsum, row, cursor, N);
    hipLaunchKernelGGL(scatter_kernel, dim3((E + 255) / 256), blk, 0, stream,
                       src_arr, dst_arr, cursor, src_sorted, E, N);

    // ---- input transform: h0 = elu(x @ w_in + b_in) ----
    {
        dim3 grid(HID / 64, (N + 63) / 64);
        hipLaunchKernelGGL((gemm_kernel<1, float>), grid, blk, 0, stream,
                           x, w_in, b_in, h0, N, F_IN, HID);
    }
    // ---- layer 1 transforms -> bf16 ----
    {
        dim3 grid(HC1 / 64, (N + 63) / 64);
        hipLaunchKernelGGL((gemm_kernel<0, __hip_bfloat16>), grid, blk, 0, stream,
                           h0, wl1, (const float*)nullptr, xl1, N, HID, HC1);
        hipLaunchKernelGGL((gemm_kernel<0, __hip_bfloat16>), grid, blk, 0, stream,
                           h0, wr1, (const float*)nullptr, xr1, N, HID, HC1);
    }
    // ---- fused layer 1 (gather + online softmax + bias + elu) ----
    {
        dim3 grid((N + 3) / 4);
        hipLaunchKernelGGL(gatv2_l1_fused_kernel, grid, blk, 0, stream,
                           xl1, xr1, row, src_sorted, att1, b1, out1, N);
    }
    // ---- layer 2 transforms (f32) ----
    {
        dim3 grid(HID / 64, (N + 63) / 64);
        hipLaunchKernelGGL((gemm_kernel<0, float>), grid, blk, 0, stream,
                           out1, wl2, (const float*)nullptr, xl2, N, HC1, HID);
        hipLaunchKernelGGL((gemm_kernel<0, float>), grid, blk, 0, stream,
                           out1, wr2, (const float*)nullptr, xr2, N, HC1, HID);
    }
    // ---- fused layer 2 + classifier + log_softmax -> d_out ----
    {
        dim3 grid((N + 3) / 4);
        hipLaunchKernelGGL(gatv2_l2_final_kernel, grid, blk, 0, stream,
                           xl2, xr2, row, src_sorted, att2, b2, w_out, b_out, out, N);
    }
}

// Round 5
// 647.232 us; speedup vs baseline: 4.7823x; 1.5461x over previous
//
#include <hip/hip_runtime.h>
#include <hip/hip_bf16.h>
#include <math.h>

// Problem constants (from reference)
#define F_IN   128
#define HID    128
#define HEADS  4
#define HC1    (HEADS*HID)   // 512
#define CLASSES 2
#define NEG_SLOPE 0.2f

#define SCAN_CHUNK 2048

typedef __attribute__((ext_vector_type(8))) short short8;
typedef __attribute__((ext_vector_type(4))) float f32x4;

// ---------------------------------------------------------------------------
// CSR build: deg histogram -> exclusive scan -> scatter src ids by dst
// ---------------------------------------------------------------------------
__global__ void zero_int_kernel(int* __restrict__ p, int n) {
    int i = blockIdx.x * blockDim.x + threadIdx.x;
    int stride = gridDim.x * blockDim.x;
    for (; i < n; i += stride) p[i] = 0;
}

__global__ void deg_kernel(const int* __restrict__ dst_arr, int* __restrict__ deg,
                           int E, int N) {
    int e = blockIdx.x * blockDim.x + threadIdx.x;
    if (e >= E) return;
    int d = dst_arr[e];
    if ((unsigned)d >= (unsigned)N) d = 0;
    atomicAdd(&deg[d], 1);
}

__global__ void scan_partial_kernel(const int* __restrict__ deg, int* __restrict__ bsum, int n) {
    __shared__ int sdata[256];
    int b = blockIdx.x, t = threadIdx.x;
    int base = b * SCAN_CHUNK;
    int s = 0;
    for (int i = t; i < SCAN_CHUNK; i += 256) {
        int idx = base + i;
        s += (idx < n) ? deg[idx] : 0;
    }
    sdata[t] = s;
    __syncthreads();
    for (int off = 128; off; off >>= 1) {
        if (t < off) sdata[t] += sdata[t + off];
        __syncthreads();
    }
    if (t == 0) bsum[b] = sdata[0];
}

__global__ void scan_bsums_kernel(int* __restrict__ bsum, int nb, int* __restrict__ row, int n) {
    if (blockIdx.x == 0 && threadIdx.x == 0) {
        int acc = 0;
        for (int i = 0; i < nb; ++i) { int v = bsum[i]; bsum[i] = acc; acc += v; }
        row[n] = acc;   // total edge count
    }
}

__global__ void scan_final_kernel(const int* __restrict__ deg, const int* __restrict__ bsum,
                                  int* __restrict__ row, int* __restrict__ cursor, int n) {
    __shared__ int tsum[256];
    int b = blockIdx.x, t = threadIdx.x;
    int base = b * SCAN_CHUNK + t * 8;
    int local[8];
    int s = 0;
    #pragma unroll
    for (int k = 0; k < 8; ++k) {
        int idx = base + k;
        int v = (idx < n) ? deg[idx] : 0;
        local[k] = s;
        s += v;
    }
    tsum[t] = s;
    __syncthreads();
    for (int off = 1; off < 256; off <<= 1) {
        int v = 0;
        if (t >= off) v = tsum[t - off];
        __syncthreads();
        if (t >= off) tsum[t] += v;
        __syncthreads();
    }
    int texcl = (t == 0) ? 0 : tsum[t - 1];
    int boff = bsum[b];
    #pragma unroll
    for (int k = 0; k < 8; ++k) {
        int idx = base + k;
        if (idx < n) {
            int v = boff + texcl + local[k];
            row[idx] = v;
            cursor[idx] = v;
        }
    }
}

__global__ void scatter_kernel(const int* __restrict__ src_arr, const int* __restrict__ dst_arr,
                               int* __restrict__ cursor, int* __restrict__ src_sorted,
                               int E, int N) {
    int e = blockIdx.x * blockDim.x + threadIdx.x;
    if (e >= E) return;
    int s = src_arr[e], d = dst_arr[e];
    if ((unsigned)s >= (unsigned)N) s = 0;
    if ((unsigned)d >= (unsigned)N) d = 0;
    int pos = atomicAdd(&cursor[d], 1);
    src_sorted[pos] = s;
}

// ---------------------------------------------------------------------------
// weight prep: wT[n][k] = (bf16) w[k][n]
// ---------------------------------------------------------------------------
__global__ void transpose_to_bf16_kernel(const float* __restrict__ w,
                                         __hip_bfloat16* __restrict__ wT,
                                         int K, int N) {
    int t = blockIdx.x * blockDim.x + threadIdx.x;
    if (t >= K * N) return;
    int n = t / K, k = t % K;
    wT[t] = __float2bfloat16(w[(size_t)k * N + n]);
}

__global__ void f32_to_bf16_kernel(const float* __restrict__ in,
                                   __hip_bfloat16* __restrict__ outb, int n) {
    int i = blockIdx.x * blockDim.x + threadIdx.x;
    int stride = gridDim.x * blockDim.x;
    short* ob = (short*)outb;
    for (int base = i * 4; base < n; base += stride * 4) {
        float4 v = *(const float4*)(in + base);
        __hip_bfloat16 h0 = __float2bfloat16(v.x);
        __hip_bfloat16 h1 = __float2bfloat16(v.y);
        __hip_bfloat16 h2 = __float2bfloat16(v.z);
        __hip_bfloat16 h3 = __float2bfloat16(v.w);
        short4 sv;
        sv.x = *reinterpret_cast<short*>(&h0);
        sv.y = *reinterpret_cast<short*>(&h1);
        sv.z = *reinterpret_cast<short*>(&h2);
        sv.w = *reinterpret_cast<short*>(&h3);
        *(short4*)(ob + base) = sv;
    }
}

// ---------------------------------------------------------------------------
// fp32 tiled GEMM (kept only for the input transform, K=128 N=128)
// ---------------------------------------------------------------------------
template<int ACT, typename OutT>
__global__ __launch_bounds__(256) void gemm_kernel(
    const float* __restrict__ A, const float* __restrict__ B,
    const float* __restrict__ bias, OutT* __restrict__ C,
    int M, int K, int N)
{
    const int tx = threadIdx.x & 15;
    const int ty = threadIdx.x >> 4;
    const int row0 = blockIdx.y * 64;
    const int col0 = blockIdx.x * 64;

    __shared__ float As[16][68];
    __shared__ float Bs[16][68];

    float acc[4][4] = {};

    for (int k0 = 0; k0 < K; k0 += 16) {
        #pragma unroll
        for (int idx = threadIdx.x; idx < 64 * 16; idx += 256) {
            int r = idx >> 4, c = idx & 15;
            int gr = row0 + r;
            float v = (gr < M) ? A[(size_t)gr * K + (k0 + c)] : 0.0f;
            As[c][r] = v;
        }
        #pragma unroll
        for (int idx = threadIdx.x; idx < 16 * 64; idx += 256) {
            int r = idx >> 6, c = idx & 63;
            Bs[r][c] = B[(size_t)(k0 + r) * N + (col0 + c)];
        }
        __syncthreads();
        #pragma unroll
        for (int k = 0; k < 16; ++k) {
            float a[4], b[4];
            #pragma unroll
            for (int i = 0; i < 4; ++i) a[i] = As[k][ty * 4 + i];
            #pragma unroll
            for (int j = 0; j < 4; ++j) b[j] = Bs[k][tx * 4 + j];
            #pragma unroll
            for (int i = 0; i < 4; ++i)
                #pragma unroll
                for (int j = 0; j < 4; ++j)
                    acc[i][j] += a[i] * b[j];
        }
        __syncthreads();
    }

    #pragma unroll
    for (int i = 0; i < 4; ++i) {
        int r = row0 + ty * 4 + i;
        if (r >= M) continue;
        #pragma unroll
        for (int j = 0; j < 4; ++j) {
            int c = col0 + tx * 4 + j;
            float v = acc[i][j] + (bias ? bias[c] : 0.0f);
            if (ACT == 1) v = (v > 0.0f) ? v : expm1f(v);
            C[(size_t)r * N + c] = (OutT)v;
        }
    }
}

// ---------------------------------------------------------------------------
// bf16 MFMA GEMM: C[M,N] = A[M,K] @ B[K,N], A bf16 [M,K], BT bf16 [N,K].
// BM=128, BN=64, BK=64, 4 waves (2x2), each wave 64x32 via 4x2 16x16x32 frags.
// LDS stride 72 bf16 (pad 8) -> 2-way bank conflict (free).
// ---------------------------------------------------------------------------
template<typename OutT>
__global__ __launch_bounds__(256) void mfma_gemm_kernel(
    const __hip_bfloat16* __restrict__ A,
    const __hip_bfloat16* __restrict__ BT,
    OutT* __restrict__ C,
    int M, int K, int N)
{
    constexpr int BM = 128, BN = 64, BK = 64, LDA = 72;
    __shared__ __align__(16) short As[BM * LDA];
    __shared__ __align__(16) short Bs[BN * LDA];

    const int tid  = threadIdx.x;
    const int lane = tid & 63;
    const int wid  = tid >> 6;
    const int wm   = wid >> 1;           // 0..1
    const int wn   = wid & 1;            // 0..1
    const int fr   = lane & 15;          // frag row (A) / col (B)
    const int fk   = (lane >> 4) * 8;    // k offset within 32

    const int row0 = blockIdx.y * BM;
    const int col0 = blockIdx.x * BN;

    const short* Ag = (const short*)A;
    const short* Bg = (const short*)BT;

    f32x4 acc[4][2] = {};

    for (int k0 = 0; k0 < K; k0 += BK) {
        // stage A tile: 128 x 64 bf16 (1024 chunks of 8)
        #pragma unroll
        for (int it = 0; it < 4; ++it) {
            int chunk = it * 256 + tid;
            int r = chunk >> 3, c = chunk & 7;
            int gr = row0 + r;
            short8 v = {0, 0, 0, 0, 0, 0, 0, 0};
            if (gr < M) v = *(const short8*)(Ag + (size_t)gr * K + k0 + c * 8);
            *(short8*)(&As[r * LDA + c * 8]) = v;
        }
        // stage B^T tile: 64 x 64 (512 chunks of 8); N,K are multiples of tile
        #pragma unroll
        for (int it = 0; it < 2; ++it) {
            int chunk = it * 256 + tid;
            int n = chunk >> 3, c = chunk & 7;
            short8 v = *(const short8*)(Bg + (size_t)(col0 + n) * K + k0 + c * 8);
            *(short8*)(&Bs[n * LDA + c * 8]) = v;
        }
        __syncthreads();
        #pragma unroll
        for (int kk = 0; kk < 2; ++kk) {
            short8 af[4], bf[2];
            #pragma unroll
            for (int i = 0; i < 4; ++i)
                af[i] = *(const short8*)(&As[(wm * 64 + i * 16 + fr) * LDA + kk * 32 + fk]);
            #pragma unroll
            for (int j = 0; j < 2; ++j)
                bf[j] = *(const short8*)(&Bs[(wn * 32 + j * 16 + fr) * LDA + kk * 32 + fk]);
            #pragma unroll
            for (int i = 0; i < 4; ++i)
                #pragma unroll
                for (int j = 0; j < 2; ++j)
                    acc[i][j] = __builtin_amdgcn_mfma_f32_16x16x32_bf16(af[i], bf[j], acc[i][j], 0, 0, 0);
        }
        __syncthreads();
    }

    // C/D layout: col = lane&15, row = (lane>>4)*4 + reg   [m89 verified]
    const int crow = row0 + wm * 64;
    const int ccol = col0 + wn * 32;
    #pragma unroll
    for (int i = 0; i < 4; ++i) {
        #pragma unroll
        for (int j = 0; j < 2; ++j) {
            int col = ccol + j * 16 + (lane & 15);
            #pragma unroll
            for (int reg = 0; reg < 4; ++reg) {
                int r = crow + i * 16 + (lane >> 4) * 4 + reg;
                if (r < M) C[(size_t)r * N + col] = (OutT)acc[i][j][reg];
            }
        }
    }
}

// ---------------------------------------------------------------------------
// Fused GATv2 layer 1: one wave per dst node, CSR gather, online softmax.
// xl/xr bf16 [N,512]. out1 = elu(agg + b1) -> bf16 [N,512].
// Lane l owns channels [8l, 8l+8); head = l/16; per-head reduce = 16-lane group.
// ---------------------------------------------------------------------------
__global__ __launch_bounds__(256) void gatv2_l1_fused_kernel(
    const __hip_bfloat16* __restrict__ xl, const __hip_bfloat16* __restrict__ xr,
    const int* __restrict__ row, const int* __restrict__ src_sorted,
    const float* __restrict__ att, const float* __restrict__ b1,
    __hip_bfloat16* __restrict__ out1, int N)
{
    int d = blockIdx.x * 4 + (threadIdx.x >> 6);
    if (d >= N) return;
    int lane = threadIdx.x & 63;
    int cbase = lane * 8;

    float xrd[8], attv[8];
    {
        uint4 raw = *reinterpret_cast<const uint4*>(xr + (size_t)d * HC1 + cbase);
        const unsigned* u = reinterpret_cast<const unsigned*>(&raw);
        #pragma unroll
        for (int j = 0; j < 4; ++j) {
            xrd[2 * j]     = __uint_as_float(u[j] << 16);
            xrd[2 * j + 1] = __uint_as_float(u[j] & 0xffff0000u);
        }
        #pragma unroll
        for (int k = 0; k < 8; ++k) attv[k] = att[cbase + k];
    }

    float m = -__builtin_huge_valf();
    float s = 0.0f;
    float o[8] = {};

    int rs = row[d], re = row[d + 1];

    for (int it = rs - 1; it < re; ++it) {
        int srcn = (it < rs) ? d : src_sorted[it];
        float v[8];
        uint4 raw = *reinterpret_cast<const uint4*>(xl + (size_t)srcn * HC1 + cbase);
        const unsigned* u = reinterpret_cast<const unsigned*>(&raw);
        #pragma unroll
        for (int j = 0; j < 4; ++j) {
            v[2 * j]     = __uint_as_float(u[j] << 16);
            v[2 * j + 1] = __uint_as_float(u[j] & 0xffff0000u);
        }
        float t = 0.0f;
        #pragma unroll
        for (int k = 0; k < 8; ++k) {
            float e = v[k] + xrd[k];
            e = (e > 0.0f) ? e : NEG_SLOPE * e;
            t = fmaf(e, attv[k], t);
        }
        t += __shfl_xor(t, 1);
        t += __shfl_xor(t, 2);
        t += __shfl_xor(t, 4);
        t += __shfl_xor(t, 8);
        if (t > m) {
            float r = __expf(m - t);
            s *= r;
            #pragma unroll
            for (int k = 0; k < 8; ++k) o[k] *= r;
            m = t;
        }
        float p = __expf(t - m);
        s += p;
        #pragma unroll
        for (int k = 0; k < 8; ++k) o[k] = fmaf(p, v[k], o[k]);
    }

    float inv = 1.0f / (s + 1e-16f);
    short8 sv;
    #pragma unroll
    for (int k = 0; k < 8; ++k) {
        float val = o[k] * inv + b1[cbase + k];
        val = (val > 0.0f) ? val : expm1f(val);
        __hip_bfloat16 hb = __float2bfloat16(val);
        sv[k] = *reinterpret_cast<short*>(&hb);
    }
    *(short8*)((short*)out1 + (size_t)d * HC1 + cbase) = sv;
}

// ---------------------------------------------------------------------------
// Fused GATv2 layer 2 (H=1) + classifier + log_softmax: one wave per node.
// xl2/xr2 f32 [N,128]. Lane l owns channels [2l, 2l+2). Writes d_out [N,2].
// ---------------------------------------------------------------------------
__global__ __launch_bounds__(256) void gatv2_l2_final_kernel(
    const float* __restrict__ xl2, const float* __restrict__ xr2,
    const int* __restrict__ row, const int* __restrict__ src_sorted,
    const float* __restrict__ att2, const float* __restrict__ b2,
    const float* __restrict__ w_out, const float* __restrict__ b_out,
    float* __restrict__ out, int N)
{
    int d = blockIdx.x * 4 + (threadIdx.x >> 6);
    if (d >= N) return;
    int lane = threadIdx.x & 63;
    int c0 = lane * 2;

    float2 xrd  = *reinterpret_cast<const float2*>(xr2 + (size_t)d * HID + c0);
    float2 attv = *reinterpret_cast<const float2*>(att2 + c0);

    float m = -__builtin_huge_valf();
    float s = 0.0f;
    float o0 = 0.0f, o1 = 0.0f;

    int rs = row[d], re = row[d + 1];
    for (int it = rs - 1; it < re; ++it) {
        int srcn = (it < rs) ? d : src_sorted[it];
        float2 v = *reinterpret_cast<const float2*>(xl2 + (size_t)srcn * HID + c0);
        float e0 = v.x + xrd.x; e0 = (e0 > 0.0f) ? e0 : NEG_SLOPE * e0;
        float e1 = v.y + xrd.y; e1 = (e1 > 0.0f) ? e1 : NEG_SLOPE * e1;
        float t = fmaf(e0, attv.x, e1 * attv.y);
        #pragma unroll
        for (int off = 32; off; off >>= 1) t += __shfl_xor(t, off);
        if (t > m) {
            float r = __expf(m - t);
            s *= r; o0 *= r; o1 *= r;
            m = t;
        }
        float p = __expf(t - m);
        s += p;
        o0 = fmaf(p, v.x, o0);
        o1 = fmaf(p, v.y, o1);
    }

    float inv = 1.0f / (s + 1e-16f);
    float h0v = o0 * inv + b2[c0];
    float h1v = o1 * inv + b2[c0 + 1];
    h0v = (h0v > 0.0f) ? h0v : expm1f(h0v);
    h1v = (h1v > 0.0f) ? h1v : expm1f(h1v);

    float a0 = fmaf(h0v, w_out[c0 * 2 + 0], h1v * w_out[(c0 + 1) * 2 + 0]);
    float a1 = fmaf(h0v, w_out[c0 * 2 + 1], h1v * w_out[(c0 + 1) * 2 + 1]);
    #pragma unroll
    for (int off = 32; off; off >>= 1) {
        a0 += __shfl_xor(a0, off);
        a1 += __shfl_xor(a1, off);
    }
    if (lane == 0) {
        float z0 = a0 + b_out[0];
        float z1 = a1 + b_out[1];
        float mx = fmaxf(z0, z1);
        float lse = mx + logf(__expf(z0 - mx) + __expf(z1 - mx));
        out[(size_t)d * CLASSES + 0] = z0 - lse;
        out[(size_t)d * CLASSES + 1] = z1 - lse;
    }
}

// ---------------------------------------------------------------------------
// launch
// ---------------------------------------------------------------------------
extern "C" void kernel_launch(void* const* d_in, const int* in_sizes, int n_in,
                              void* d_out, int out_size, void* d_ws, size_t ws_size,
                              hipStream_t stream)
{
    const float* x     = (const float*)d_in[0];
    const int*   eidx  = (const int*)d_in[1];
    const float* w_in  = (const float*)d_in[2];
    const float* b_in  = (const float*)d_in[3];
    const float* wl1   = (const float*)d_in[4];
    const float* wr1   = (const float*)d_in[5];
    const float* att1  = (const float*)d_in[6];
    const float* b1    = (const float*)d_in[7];
    const float* wl2   = (const float*)d_in[8];
    const float* wr2   = (const float*)d_in[9];
    const float* att2  = (const float*)d_in[10];
    const float* b2    = (const float*)d_in[11];
    const float* w_out = (const float*)d_in[12];
    const float* b_out = (const float*)d_in[13];
    float* out = (float*)d_out;

    const int N = in_sizes[0] / F_IN;      // 50000
    const int E = in_sizes[1] / 2;         // 800000
    const int* src_arr = eidx;
    const int* dst_arr = eidx + E;

    // ---- workspace layout (peak ~171 MB) ----
    size_t off = 0;
    auto alloc = [&](size_t bytes) -> char* {
        char* ptr = (char*)d_ws + off;
        off += (bytes + 255) & ~(size_t)255;
        return ptr;
    };
    int* row        = (int*)alloc((size_t)(N + 1) * 4);
    int* cursor     = (int*)alloc((size_t)N * 4);
    int* deg        = (int*)alloc((size_t)N * 4);
    int* bsum       = (int*)alloc(64 * 4);
    int* src_sorted = (int*)alloc((size_t)E * 4);
    __hip_bfloat16* wT1l = (__hip_bfloat16*)alloc((size_t)HID * HC1 * 2);
    __hip_bfloat16* wT1r = (__hip_bfloat16*)alloc((size_t)HID * HC1 * 2);
    __hip_bfloat16* wT2l = (__hip_bfloat16*)alloc((size_t)HC1 * HID * 2);
    __hip_bfloat16* wT2r = (__hip_bfloat16*)alloc((size_t)HC1 * HID * 2);
    float*          h0   = (float*)alloc((size_t)N * HID * 4);          // -> xl2
    __hip_bfloat16* h0b  = (__hip_bfloat16*)alloc((size_t)N * HID * 2);
    __hip_bfloat16* xl1  = (__hip_bfloat16*)alloc((size_t)N * HC1 * 2); // -> xr2
    __hip_bfloat16* xr1  = (__hip_bfloat16*)alloc((size_t)N * HC1 * 2);
    __hip_bfloat16* out1 = (__hip_bfloat16*)alloc((size_t)N * HC1 * 2);

    float* xl2 = h0;            // h0 fp32 dead after h0b conversion
    float* xr2 = (float*)xl1;   // xl1 dead after fused layer-1

    dim3 blk(256);
    const int NB_SCAN = (N + SCAN_CHUNK - 1) / SCAN_CHUNK;

    // ---- CSR build ----
    hipLaunchKernelGGL(zero_int_kernel, dim3(64), blk, 0, stream, deg, N);
    hipLaunchKernelGGL(deg_kernel, dim3((E + 255) / 256), blk, 0, stream, dst_arr, deg, E, N);
    hipLaunchKernelGGL(scan_partial_kernel, dim3(NB_SCAN), blk, 0, stream, deg, bsum, N);
    hipLaunchKernelGGL(scan_bsums_kernel, dim3(1), blk, 0, stream, bsum, NB_SCAN, row, N);
    hipLaunchKernelGGL(scan_final_kernel, dim3(NB_SCAN), blk, 0, stream, deg, bsum, row, cursor, N);
    hipLaunchKernelGGL(scatter_kernel, dim3((E + 255) / 256), blk, 0, stream,
                       src_arr, dst_arr, cursor, src_sorted, E, N);

    // ---- weight prep (bf16 transposed) ----
    {
        dim3 gw((HID * HC1 + 255) / 256);
        hipLaunchKernelGGL(transpose_to_bf16_kernel, gw, blk, 0, stream, wl1, wT1l, HID, HC1);
        hipLaunchKernelGGL(transpose_to_bf16_kernel, gw, blk, 0, stream, wr1, wT1r, HID, HC1);
        hipLaunchKernelGGL(transpose_to_bf16_kernel, gw, blk, 0, stream, wl2, wT2l, HC1, HID);
        hipLaunchKernelGGL(transpose_to_bf16_kernel, gw, blk, 0, stream, wr2, wT2r, HC1, HID);
    }

    // ---- input transform (fp32): h0 = elu(x @ w_in + b_in); then -> bf16 ----
    {
        dim3 grid(HID / 64, (N + 63) / 64);
        hipLaunchKernelGGL((gemm_kernel<1, float>), grid, blk, 0, stream,
                           x, w_in, b_in, h0, N, F_IN, HID);
        hipLaunchKernelGGL(f32_to_bf16_kernel, dim3(2048), blk, 0, stream, h0, h0b, N * HID);
    }
    // ---- layer 1 transforms: bf16 MFMA ----
    {
        dim3 grid(HC1 / 64, (N + 127) / 128);
        hipLaunchKernelGGL((mfma_gemm_kernel<__hip_bfloat16>), grid, blk, 0, stream,
                           h0b, wT1l, xl1, N, HID, HC1);
        hipLaunchKernelGGL((mfma_gemm_kernel<__hip_bfloat16>), grid, blk, 0, stream,
                           h0b, wT1r, xr1, N, HID, HC1);
    }
    // ---- fused layer 1 (gather + online softmax + bias + elu) -> bf16 ----
    {
        dim3 grid((N + 3) / 4);
        hipLaunchKernelGGL(gatv2_l1_fused_kernel, grid, blk, 0, stream,
                           xl1, xr1, row, src_sorted, att1, b1, out1, N);
    }
    // ---- layer 2 transforms: bf16 MFMA -> fp32 out ----
    {
        dim3 grid(HID / 64, (N + 127) / 128);
        hipLaunchKernelGGL((mfma_gemm_kernel<float>), grid, blk, 0, stream,
                           out1, wT2l, xl2, N, HC1, HID);
        hipLaunchKernelGGL((mfma_gemm_kernel<float>), grid, blk, 0, stream,
                           out1, wT2r, xr2, N, HC1, HID);
    }
    // ---- fused layer 2 + classifier + log_softmax -> d_out ----
    {
        dim3 grid((N + 3) / 4);
        hipLaunchKernelGGL(gatv2_l2_final_kernel, grid, blk, 0, stream,
                           xl2, xr2, row, src_sorted, att2, b2, w_out, b_out, out, N);
    }
}

// Round 6
// 603.198 us; speedup vs baseline: 5.1314x; 1.0730x over previous
//
#include <hip/hip_runtime.h>
#include <hip/hip_bf16.h>
#include <math.h>

// Problem constants (from reference)
#define F_IN   128
#define HID    128
#define HEADS  4
#define HC1    (HEADS*HID)   // 512
#define CLASSES 2
#define NEG_SLOPE 0.2f

#define SCAN_CHUNK 2048

typedef __attribute__((ext_vector_type(8))) short short8;
typedef __attribute__((ext_vector_type(4))) float f32x4;

// ---------------------------------------------------------------------------
// CSR build: deg histogram -> exclusive scan -> scatter src ids by dst
// ---------------------------------------------------------------------------
__global__ void zero_int_kernel(int* __restrict__ p, int n) {
    int i = blockIdx.x * blockDim.x + threadIdx.x;
    int stride = gridDim.x * blockDim.x;
    for (; i < n; i += stride) p[i] = 0;
}

__global__ void deg_kernel(const int* __restrict__ dst_arr, int* __restrict__ deg,
                           int E, int N) {
    int e = blockIdx.x * blockDim.x + threadIdx.x;
    if (e >= E) return;
    int d = dst_arr[e];
    if ((unsigned)d >= (unsigned)N) d = 0;
    atomicAdd(&deg[d], 1);
}

__global__ void scan_partial_kernel(const int* __restrict__ deg, int* __restrict__ bsum, int n) {
    __shared__ int sdata[256];
    int b = blockIdx.x, t = threadIdx.x;
    int base = b * SCAN_CHUNK;
    int s = 0;
    for (int i = t; i < SCAN_CHUNK; i += 256) {
        int idx = base + i;
        s += (idx < n) ? deg[idx] : 0;
    }
    sdata[t] = s;
    __syncthreads();
    for (int off = 128; off; off >>= 1) {
        if (t < off) sdata[t] += sdata[t + off];
        __syncthreads();
    }
    if (t == 0) bsum[b] = sdata[0];
}

__global__ void scan_bsums_kernel(int* __restrict__ bsum, int nb, int* __restrict__ row, int n) {
    if (blockIdx.x == 0 && threadIdx.x == 0) {
        int acc = 0;
        for (int i = 0; i < nb; ++i) { int v = bsum[i]; bsum[i] = acc; acc += v; }
        row[n] = acc;
    }
}

__global__ void scan_final_kernel(const int* __restrict__ deg, const int* __restrict__ bsum,
                                  int* __restrict__ row, int* __restrict__ cursor, int n) {
    __shared__ int tsum[256];
    int b = blockIdx.x, t = threadIdx.x;
    int base = b * SCAN_CHUNK + t * 8;
    int local[8];
    int s = 0;
    #pragma unroll
    for (int k = 0; k < 8; ++k) {
        int idx = base + k;
        int v = (idx < n) ? deg[idx] : 0;
        local[k] = s;
        s += v;
    }
    tsum[t] = s;
    __syncthreads();
    for (int off = 1; off < 256; off <<= 1) {
        int v = 0;
        if (t >= off) v = tsum[t - off];
        __syncthreads();
        if (t >= off) tsum[t] += v;
        __syncthreads();
    }
    int texcl = (t == 0) ? 0 : tsum[t - 1];
    int boff = bsum[b];
    #pragma unroll
    for (int k = 0; k < 8; ++k) {
        int idx = base + k;
        if (idx < n) {
            int v = boff + texcl + local[k];
            row[idx] = v;
            cursor[idx] = v;
        }
    }
}

__global__ void scatter_kernel(const int* __restrict__ src_arr, const int* __restrict__ dst_arr,
                               int* __restrict__ cursor, int* __restrict__ src_sorted,
                               int E, int N) {
    int e = blockIdx.x * blockDim.x + threadIdx.x;
    if (e >= E) return;
    int s = src_arr[e], d = dst_arr[e];
    if ((unsigned)s >= (unsigned)N) s = 0;
    if ((unsigned)d >= (unsigned)N) d = 0;
    int pos = atomicAdd(&cursor[d], 1);
    src_sorted[pos] = s;
}

// ---------------------------------------------------------------------------
// weight prep: wT[n][k] = (bf16) w[k][n]   (write into combined buffers)
// ---------------------------------------------------------------------------
__global__ void transpose_to_bf16_kernel(const float* __restrict__ w,
                                         __hip_bfloat16* __restrict__ wT,
                                         int K, int N) {
    int t = blockIdx.x * blockDim.x + threadIdx.x;
    if (t >= K * N) return;
    int n = t / K, k = t % K;
    wT[t] = __float2bfloat16(w[(size_t)k * N + n]);
}

__global__ void f32_to_bf16_kernel(const float* __restrict__ in,
                                   __hip_bfloat16* __restrict__ outb, int n) {
    int i = blockIdx.x * blockDim.x + threadIdx.x;
    int stride = gridDim.x * blockDim.x;
    short* ob = (short*)outb;
    for (int base = i * 4; base < n; base += stride * 4) {
        float4 v = *(const float4*)(in + base);
        __hip_bfloat16 h0 = __float2bfloat16(v.x);
        __hip_bfloat16 h1 = __float2bfloat16(v.y);
        __hip_bfloat16 h2 = __float2bfloat16(v.z);
        __hip_bfloat16 h3 = __float2bfloat16(v.w);
        short4 sv;
        sv.x = *reinterpret_cast<short*>(&h0);
        sv.y = *reinterpret_cast<short*>(&h1);
        sv.z = *reinterpret_cast<short*>(&h2);
        sv.w = *reinterpret_cast<short*>(&h3);
        *(short4*)(ob + base) = sv;
    }
}

// ---------------------------------------------------------------------------
// bf16 MFMA GEMM: C[M,N] = A[M,K] @ BT^T (+bias, +elu), A bf16 [M,K],
// BT bf16 [N,K]. BM=128, BN=64, BK=64, 4 waves (2x2); LDS stride 72 (pad 8).
// ---------------------------------------------------------------------------
template<int ACT, typename OutT>   // ACT: 0 none, 1 elu
__global__ __launch_bounds__(256) void mfma_gemm_kernel(
    const __hip_bfloat16* __restrict__ A,
    const __hip_bfloat16* __restrict__ BT,
    const float* __restrict__ bias,
    OutT* __restrict__ C,
    int M, int K, int N)
{
    constexpr int BM = 128, BN = 64, BK = 64, LDA = 72;
    __shared__ __align__(16) short As[BM * LDA];
    __shared__ __align__(16) short Bs[BN * LDA];

    const int tid  = threadIdx.x;
    const int lane = tid & 63;
    const int wid  = tid >> 6;
    const int wm   = wid >> 1;
    const int wn   = wid & 1;
    const int fr   = lane & 15;
    const int fk   = (lane >> 4) * 8;

    const int row0 = blockIdx.y * BM;
    const int col0 = blockIdx.x * BN;

    const short* Ag = (const short*)A;
    const short* Bg = (const short*)BT;

    f32x4 acc[4][2] = {};

    for (int k0 = 0; k0 < K; k0 += BK) {
        #pragma unroll
        for (int it = 0; it < 4; ++it) {
            int chunk = it * 256 + tid;
            int r = chunk >> 3, c = chunk & 7;
            int gr = row0 + r;
            short8 v = {0, 0, 0, 0, 0, 0, 0, 0};
            if (gr < M) v = *(const short8*)(Ag + (size_t)gr * K + k0 + c * 8);
            *(short8*)(&As[r * LDA + c * 8]) = v;
        }
        #pragma unroll
        for (int it = 0; it < 2; ++it) {
            int chunk = it * 256 + tid;
            int n = chunk >> 3, c = chunk & 7;
            short8 v = *(const short8*)(Bg + (size_t)(col0 + n) * K + k0 + c * 8);
            *(short8*)(&Bs[n * LDA + c * 8]) = v;
        }
        __syncthreads();
        #pragma unroll
        for (int kk = 0; kk < 2; ++kk) {
            short8 af[4], bf[2];
            #pragma unroll
            for (int i = 0; i < 4; ++i)
                af[i] = *(const short8*)(&As[(wm * 64 + i * 16 + fr) * LDA + kk * 32 + fk]);
            #pragma unroll
            for (int j = 0; j < 2; ++j)
                bf[j] = *(const short8*)(&Bs[(wn * 32 + j * 16 + fr) * LDA + kk * 32 + fk]);
            #pragma unroll
            for (int i = 0; i < 4; ++i)
                #pragma unroll
                for (int j = 0; j < 2; ++j)
                    acc[i][j] = __builtin_amdgcn_mfma_f32_16x16x32_bf16(af[i], bf[j], acc[i][j], 0, 0, 0);
        }
        __syncthreads();
    }

    // C/D layout: col = lane&15, row = (lane>>4)*4 + reg
    const int crow = row0 + wm * 64;
    const int ccol = col0 + wn * 32;
    #pragma unroll
    for (int i = 0; i < 4; ++i) {
        #pragma unroll
        for (int j = 0; j < 2; ++j) {
            int col = ccol + j * 16 + (lane & 15);
            float bv = bias ? bias[col] : 0.0f;
            #pragma unroll
            for (int reg = 0; reg < 4; ++reg) {
                int r = crow + i * 16 + (lane >> 4) * 4 + reg;
                if (r < M) {
                    float v = acc[i][j][reg] + bv;
                    if (ACT == 1) v = (v > 0.0f) ? v : expm1f(v);
                    C[(size_t)r * N + col] = (OutT)v;
                }
            }
        }
    }
}

// ---------------------------------------------------------------------------
// Fused GATv2 layer 1: one wave per dst node, CSR gather, online softmax.
// xlr bf16 [N,1024] (cols 0..511 = xl, 512..1023 = xr).
// out1 = elu(agg + b1) -> bf16 [N,512].
// Lane l owns channels [8l,8l+8); head = l/16; 16-lane-group reduce.
// ---------------------------------------------------------------------------
__global__ __launch_bounds__(256) void gatv2_l1_fused_kernel(
    const __hip_bfloat16* __restrict__ xlr,
    const int* __restrict__ row, const int* __restrict__ src_sorted,
    const float* __restrict__ att, const float* __restrict__ b1,
    __hip_bfloat16* __restrict__ out1, int N)
{
    int d = blockIdx.x * 4 + (threadIdx.x >> 6);
    if (d >= N) return;
    int lane = threadIdx.x & 63;
    int cbase = lane * 8;
    const short* base = (const short*)xlr;

    float xrd[8], attv[8];
    {
        uint4 raw = *reinterpret_cast<const uint4*>(base + (size_t)d * 1024 + 512 + cbase);
        const unsigned* u = reinterpret_cast<const unsigned*>(&raw);
        #pragma unroll
        for (int j = 0; j < 4; ++j) {
            xrd[2 * j]     = __uint_as_float(u[j] << 16);
            xrd[2 * j + 1] = __uint_as_float(u[j] & 0xffff0000u);
        }
        #pragma unroll
        for (int k = 0; k < 8; ++k) attv[k] = att[cbase + k];
    }

    float m = -__builtin_huge_valf();
    float s = 0.0f;
    float o[8] = {};

    int rs = row[d], re = row[d + 1];

    // prefetched gather: self-loop first, then CSR edges
    uint4 raw = *reinterpret_cast<const uint4*>(base + (size_t)d * 1024 + cbase);
    for (int it = rs - 1; it < re; ++it) {
        uint4 cur = raw;
        if (it + 1 < re) {
            int sn = src_sorted[it + 1];
            raw = *reinterpret_cast<const uint4*>(base + (size_t)sn * 1024 + cbase);
        }
        float v[8];
        const unsigned* u = reinterpret_cast<const unsigned*>(&cur);
        #pragma unroll
        for (int j = 0; j < 4; ++j) {
            v[2 * j]     = __uint_as_float(u[j] << 16);
            v[2 * j + 1] = __uint_as_float(u[j] & 0xffff0000u);
        }
        float t = 0.0f;
        #pragma unroll
        for (int k = 0; k < 8; ++k) {
            float e = v[k] + xrd[k];
            e = (e > 0.0f) ? e : NEG_SLOPE * e;
            t = fmaf(e, attv[k], t);
        }
        t += __shfl_xor(t, 1);
        t += __shfl_xor(t, 2);
        t += __shfl_xor(t, 4);
        t += __shfl_xor(t, 8);
        if (t > m) {
            float r = __expf(m - t);
            s *= r;
            #pragma unroll
            for (int k = 0; k < 8; ++k) o[k] *= r;
            m = t;
        }
        float p = __expf(t - m);
        s += p;
        #pragma unroll
        for (int k = 0; k < 8; ++k) o[k] = fmaf(p, v[k], o[k]);
    }

    float inv = 1.0f / (s + 1e-16f);
    short8 sv;
    #pragma unroll
    for (int k = 0; k < 8; ++k) {
        float val = o[k] * inv + b1[cbase + k];
        val = (val > 0.0f) ? val : expm1f(val);
        __hip_bfloat16 hb = __float2bfloat16(val);
        sv[k] = *reinterpret_cast<short*>(&hb);
    }
    *(short8*)((short*)out1 + (size_t)d * HC1 + cbase) = sv;
}

// ---------------------------------------------------------------------------
// Fused GATv2 layer 2 (H=1) + classifier + log_softmax: one wave per node.
// xlr2 bf16 [N,256] (cols 0..127 = xl2, 128..255 = xr2). Writes d_out [N,2].
// Lane l owns channels [2l,2l+2).
// ---------------------------------------------------------------------------
__global__ __launch_bounds__(256) void gatv2_l2_final_kernel(
    const __hip_bfloat16* __restrict__ xlr2,
    const int* __restrict__ row, const int* __restrict__ src_sorted,
    const float* __restrict__ att2, const float* __restrict__ b2,
    const float* __restrict__ w_out, const float* __restrict__ b_out,
    float* __restrict__ out, int N)
{
    int d = blockIdx.x * 4 + (threadIdx.x >> 6);
    if (d >= N) return;
    int lane = threadIdx.x & 63;
    int c0 = lane * 2;
    const short* base = (const short*)xlr2;

    unsigned xr_raw = *reinterpret_cast<const unsigned*>(base + (size_t)d * 256 + 128 + c0);
    float xrd0 = __uint_as_float(xr_raw << 16);
    float xrd1 = __uint_as_float(xr_raw & 0xffff0000u);
    float2 attv = *reinterpret_cast<const float2*>(att2 + c0);

    float m = -__builtin_huge_valf();
    float s = 0.0f;
    float o0 = 0.0f, o1 = 0.0f;

    int rs = row[d], re = row[d + 1];
    unsigned raw = *reinterpret_cast<const unsigned*>(base + (size_t)d * 256 + c0);
    for (int it = rs - 1; it < re; ++it) {
        unsigned cur = raw;
        if (it + 1 < re) {
            int sn = src_sorted[it + 1];
            raw = *reinterpret_cast<const unsigned*>(base + (size_t)sn * 256 + c0);
        }
        float v0 = __uint_as_float(cur << 16);
        float v1 = __uint_as_float(cur & 0xffff0000u);
        float e0 = v0 + xrd0; e0 = (e0 > 0.0f) ? e0 : NEG_SLOPE * e0;
        float e1 = v1 + xrd1; e1 = (e1 > 0.0f) ? e1 : NEG_SLOPE * e1;
        float t = fmaf(e0, attv.x, e1 * attv.y);
        #pragma unroll
        for (int off = 32; off; off >>= 1) t += __shfl_xor(t, off);
        if (t > m) {
            float r = __expf(m - t);
            s *= r; o0 *= r; o1 *= r;
            m = t;
        }
        float p = __expf(t - m);
        s += p;
        o0 = fmaf(p, v0, o0);
        o1 = fmaf(p, v1, o1);
    }

    float inv = 1.0f / (s + 1e-16f);
    float h0v = o0 * inv + b2[c0];
    float h1v = o1 * inv + b2[c0 + 1];
    h0v = (h0v > 0.0f) ? h0v : expm1f(h0v);
    h1v = (h1v > 0.0f) ? h1v : expm1f(h1v);

    float a0 = fmaf(h0v, w_out[c0 * 2 + 0], h1v * w_out[(c0 + 1) * 2 + 0]);
    float a1 = fmaf(h0v, w_out[c0 * 2 + 1], h1v * w_out[(c0 + 1) * 2 + 1]);
    #pragma unroll
    for (int off = 32; off; off >>= 1) {
        a0 += __shfl_xor(a0, off);
        a1 += __shfl_xor(a1, off);
    }
    if (lane == 0) {
        float z0 = a0 + b_out[0];
        float z1 = a1 + b_out[1];
        float mx = fmaxf(z0, z1);
        float lse = mx + logf(__expf(z0 - mx) + __expf(z1 - mx));
        out[(size_t)d * CLASSES + 0] = z0 - lse;
        out[(size_t)d * CLASSES + 1] = z1 - lse;
    }
}

// ---------------------------------------------------------------------------
// launch
// ---------------------------------------------------------------------------
extern "C" void kernel_launch(void* const* d_in, const int* in_sizes, int n_in,
                              void* d_out, int out_size, void* d_ws, size_t ws_size,
                              hipStream_t stream)
{
    const float* x     = (const float*)d_in[0];
    const int*   eidx  = (const int*)d_in[1];
    const float* w_in  = (const float*)d_in[2];
    const float* b_in  = (const float*)d_in[3];
    const float* wl1   = (const float*)d_in[4];
    const float* wr1   = (const float*)d_in[5];
    const float* att1  = (const float*)d_in[6];
    const float* b1    = (const float*)d_in[7];
    const float* wl2   = (const float*)d_in[8];
    const float* wr2   = (const float*)d_in[9];
    const float* att2  = (const float*)d_in[10];
    const float* b2    = (const float*)d_in[11];
    const float* w_out = (const float*)d_in[12];
    const float* b_out = (const float*)d_in[13];
    float* out = (float*)d_out;

    const int N = in_sizes[0] / F_IN;      // 50000
    const int E = in_sizes[1] / 2;         // 800000
    const int* src_arr = eidx;
    const int* dst_arr = eidx + E;

    // ---- workspace layout (peak ~185 MB) ----
    size_t off = 0;
    auto alloc = [&](size_t bytes) -> char* {
        char* ptr = (char*)d_ws + off;
        off += (bytes + 255) & ~(size_t)255;
        return ptr;
    };
    int* row        = (int*)alloc((size_t)(N + 1) * 4);
    int* cursor     = (int*)alloc((size_t)N * 4);
    int* deg        = (int*)alloc((size_t)N * 4);
    int* bsum       = (int*)alloc(64 * 4);
    int* src_sorted = (int*)alloc((size_t)E * 4);
    __hip_bfloat16* w_inT = (__hip_bfloat16*)alloc((size_t)F_IN * HID * 2);
    __hip_bfloat16* wT1   = (__hip_bfloat16*)alloc((size_t)2 * HC1 * HID * 2);  // [1024][128]
    __hip_bfloat16* wT2   = (__hip_bfloat16*)alloc((size_t)2 * HID * HC1 * 2);  // [256][512]
    __hip_bfloat16* xb    = (__hip_bfloat16*)alloc((size_t)N * F_IN * 2);
    __hip_bfloat16* h0b   = (__hip_bfloat16*)alloc((size_t)N * HID * 2);
    __hip_bfloat16* xlr1  = (__hip_bfloat16*)alloc((size_t)N * 2 * HC1 * 2);    // [N][1024]
    __hip_bfloat16* out1  = (__hip_bfloat16*)alloc((size_t)N * HC1 * 2);

    __hip_bfloat16* xlr2 = xlr1;   // [N][256] overlays xlr1 (dead after fused L1)

    dim3 blk(256);
    const int NB_SCAN = (N + SCAN_CHUNK - 1) / SCAN_CHUNK;

    // ---- CSR build ----
    hipLaunchKernelGGL(zero_int_kernel, dim3(64), blk, 0, stream, deg, N);
    hipLaunchKernelGGL(deg_kernel, dim3((E + 255) / 256), blk, 0, stream, dst_arr, deg, E, N);
    hipLaunchKernelGGL(scan_partial_kernel, dim3(NB_SCAN), blk, 0, stream, deg, bsum, N);
    hipLaunchKernelGGL(scan_bsums_kernel, dim3(1), blk, 0, stream, bsum, NB_SCAN, row, N);
    hipLaunchKernelGGL(scan_final_kernel, dim3(NB_SCAN), blk, 0, stream, deg, bsum, row, cursor, N);
    hipLaunchKernelGGL(scatter_kernel, dim3((E + 255) / 256), blk, 0, stream,
                       src_arr, dst_arr, cursor, src_sorted, E, N);

    // ---- weight prep (bf16 transposed, combined) ----
    {
        dim3 gw((HID * HC1 + 255) / 256);
        dim3 gwi((F_IN * HID + 255) / 256);
        hipLaunchKernelGGL(transpose_to_bf16_kernel, gwi, blk, 0, stream, w_in, w_inT, F_IN, HID);
        hipLaunchKernelGGL(transpose_to_bf16_kernel, gw, blk, 0, stream, wl1, wT1, HID, HC1);
        hipLaunchKernelGGL(transpose_to_bf16_kernel, gw, blk, 0, stream, wr1, wT1 + (size_t)HC1 * HID, HID, HC1);
        hipLaunchKernelGGL(transpose_to_bf16_kernel, gw, blk, 0, stream, wl2, wT2, HC1, HID);
        hipLaunchKernelGGL(transpose_to_bf16_kernel, gw, blk, 0, stream, wr2, wT2 + (size_t)HID * HC1, HC1, HID);
    }

    // ---- x -> bf16; input transform via MFMA with fused bias+elu ----
    hipLaunchKernelGGL(f32_to_bf16_kernel, dim3(2048), blk, 0, stream, x, xb, N * F_IN);
    {
        dim3 grid(HID / 64, (N + 127) / 128);
        hipLaunchKernelGGL((mfma_gemm_kernel<1, __hip_bfloat16>), grid, blk, 0, stream,
                           xb, w_inT, b_in, h0b, N, F_IN, HID);
    }
    // ---- layer 1 transforms: ONE combined MFMA GEMM -> xlr1 [N][1024] ----
    {
        dim3 grid(2 * HC1 / 64, (N + 127) / 128);
        hipLaunchKernelGGL((mfma_gemm_kernel<0, __hip_bfloat16>), grid, blk, 0, stream,
                           h0b, wT1, (const float*)nullptr, xlr1, N, HID, 2 * HC1);
    }
    // ---- fused layer 1 (gather + online softmax + bias + elu) -> bf16 ----
    {
        dim3 grid((N + 3) / 4);
        hipLaunchKernelGGL(gatv2_l1_fused_kernel, grid, blk, 0, stream,
                           xlr1, row, src_sorted, att1, b1, out1, N);
    }
    // ---- layer 2 transforms: ONE combined MFMA GEMM -> xlr2 [N][256] ----
    {
        dim3 grid(2 * HID / 64, (N + 127) / 128);
        hipLaunchKernelGGL((mfma_gemm_kernel<0, __hip_bfloat16>), grid, blk, 0, stream,
                           out1, wT2, (const float*)nullptr, xlr2, N, HC1, 2 * HID);
    }
    // ---- fused layer 2 + classifier + log_softmax -> d_out ----
    {
        dim3 grid((N + 3) / 4);
        hipLaunchKernelGGL(gatv2_l2_final_kernel, grid, blk, 0, stream,
                           xlr2, row, src_sorted, att2, b2, w_out, b_out, out, N);
    }
}

// Round 7
// 588.409 us; speedup vs baseline: 5.2603x; 1.0251x over previous
//
#include <hip/hip_runtime.h>
#include <hip/hip_bf16.h>
#include <math.h>

// Problem constants (from reference)
#define F_IN   128
#define HID    128
#define HEADS  4
#define HC1    (HEADS*HID)   // 512
#define CLASSES 2
#define NEG_SLOPE 0.2f
#define LOG2E 1.44269504088896340736f

#define SCAN_CHUNK 2048

typedef __attribute__((ext_vector_type(8))) short short8;
typedef __attribute__((ext_vector_type(4))) float f32x4;

// ---------------------------------------------------------------------------
// CSR build: deg histogram -> exclusive scan -> scatter src ids by dst
// ---------------------------------------------------------------------------
__global__ void zero_int_kernel(int* __restrict__ p, int n) {
    int i = blockIdx.x * blockDim.x + threadIdx.x;
    int stride = gridDim.x * blockDim.x;
    for (; i < n; i += stride) p[i] = 0;
}

__global__ void deg_kernel(const int* __restrict__ dst_arr, int* __restrict__ deg,
                           int E, int N) {
    int e = blockIdx.x * blockDim.x + threadIdx.x;
    if (e >= E) return;
    int d = dst_arr[e];
    if ((unsigned)d >= (unsigned)N) d = 0;
    atomicAdd(&deg[d], 1);
}

__global__ void scan_partial_kernel(const int* __restrict__ deg, int* __restrict__ bsum, int n) {
    __shared__ int sdata[256];
    int b = blockIdx.x, t = threadIdx.x;
    int base = b * SCAN_CHUNK;
    int s = 0;
    for (int i = t; i < SCAN_CHUNK; i += 256) {
        int idx = base + i;
        s += (idx < n) ? deg[idx] : 0;
    }
    sdata[t] = s;
    __syncthreads();
    for (int off = 128; off; off >>= 1) {
        if (t < off) sdata[t] += sdata[t + off];
        __syncthreads();
    }
    if (t == 0) bsum[b] = sdata[0];
}

__global__ void scan_bsums_kernel(int* __restrict__ bsum, int nb, int* __restrict__ row, int n) {
    if (blockIdx.x == 0 && threadIdx.x == 0) {
        int acc = 0;
        for (int i = 0; i < nb; ++i) { int v = bsum[i]; bsum[i] = acc; acc += v; }
        row[n] = acc;
    }
}

__global__ void scan_final_kernel(const int* __restrict__ deg, const int* __restrict__ bsum,
                                  int* __restrict__ row, int* __restrict__ cursor, int n) {
    __shared__ int tsum[256];
    int b = blockIdx.x, t = threadIdx.x;
    int base = b * SCAN_CHUNK + t * 8;
    int local[8];
    int s = 0;
    #pragma unroll
    for (int k = 0; k < 8; ++k) {
        int idx = base + k;
        int v = (idx < n) ? deg[idx] : 0;
        local[k] = s;
        s += v;
    }
    tsum[t] = s;
    __syncthreads();
    for (int off = 1; off < 256; off <<= 1) {
        int v = 0;
        if (t >= off) v = tsum[t - off];
        __syncthreads();
        if (t >= off) tsum[t] += v;
        __syncthreads();
    }
    int texcl = (t == 0) ? 0 : tsum[t - 1];
    int boff = bsum[b];
    #pragma unroll
    for (int k = 0; k < 8; ++k) {
        int idx = base + k;
        if (idx < n) {
            int v = boff + texcl + local[k];
            row[idx] = v;
            cursor[idx] = v;
        }
    }
}

__global__ void scatter_kernel(const int* __restrict__ src_arr, const int* __restrict__ dst_arr,
                               int* __restrict__ cursor, int* __restrict__ src_sorted,
                               int E, int N) {
    int e = blockIdx.x * blockDim.x + threadIdx.x;
    if (e >= E) return;
    int s = src_arr[e], d = dst_arr[e];
    if ((unsigned)s >= (unsigned)N) s = 0;
    if ((unsigned)d >= (unsigned)N) d = 0;
    int pos = atomicAdd(&cursor[d], 1);
    src_sorted[pos] = s;
}

// ---------------------------------------------------------------------------
// fused weight prep: transpose+bf16 all 5 weight matrices in ONE kernel.
// seg layout (element counts): w_in 128x128 | wl1 128x512 | wr1 128x512 |
//                              wl2 512x128 | wr2 512x128
// ---------------------------------------------------------------------------
__global__ void weights_prep_kernel(
    const float* __restrict__ w_in, const float* __restrict__ wl1,
    const float* __restrict__ wr1, const float* __restrict__ wl2,
    const float* __restrict__ wr2,
    __hip_bfloat16* __restrict__ w_inT, __hip_bfloat16* __restrict__ wT1l,
    __hip_bfloat16* __restrict__ wT1r, __hip_bfloat16* __restrict__ wT2l,
    __hip_bfloat16* __restrict__ wT2r)
{
    int t = blockIdx.x * blockDim.x + threadIdx.x;
    const int S0 = 128 * 128, S1 = 128 * 512;
    const float* w; __hip_bfloat16* wT; int K, Nn, idx;
    if (t < S0)                { w = w_in; wT = w_inT; K = 128; Nn = 128; idx = t; }
    else if (t < S0 + S1)      { w = wl1;  wT = wT1l;  K = 128; Nn = 512; idx = t - S0; }
    else if (t < S0 + 2 * S1)  { w = wr1;  wT = wT1r;  K = 128; Nn = 512; idx = t - S0 - S1; }
    else if (t < S0 + 3 * S1)  { w = wl2;  wT = wT2l;  K = 512; Nn = 128; idx = t - S0 - 2 * S1; }
    else if (t < S0 + 4 * S1)  { w = wr2;  wT = wT2r;  K = 512; Nn = 128; idx = t - S0 - 3 * S1; }
    else return;
    int n = idx / K, k = idx % K;
    wT[idx] = __float2bfloat16(w[(size_t)k * Nn + n]);
}

__global__ void f32_to_bf16_kernel(const float* __restrict__ in,
                                   __hip_bfloat16* __restrict__ outb, int n) {
    int i = blockIdx.x * blockDim.x + threadIdx.x;
    int stride = gridDim.x * blockDim.x;
    short* ob = (short*)outb;
    for (int base = i * 4; base < n; base += stride * 4) {
        float4 v = *(const float4*)(in + base);
        __hip_bfloat16 h0 = __float2bfloat16(v.x);
        __hip_bfloat16 h1 = __float2bfloat16(v.y);
        __hip_bfloat16 h2 = __float2bfloat16(v.z);
        __hip_bfloat16 h3 = __float2bfloat16(v.w);
        short4 sv;
        sv.x = *reinterpret_cast<short*>(&h0);
        sv.y = *reinterpret_cast<short*>(&h1);
        sv.z = *reinterpret_cast<short*>(&h2);
        sv.w = *reinterpret_cast<short*>(&h3);
        *(short4*)(ob + base) = sv;
    }
}

// ---------------------------------------------------------------------------
// bf16 MFMA GEMM (m97-style 128x128 tile): C = A @ BT^T (+bias, +elu)
// A bf16 [M,K], BT bf16 [N,K]. BM=BN=128, BK=64; 4 waves, each 64x64
// (4x4 frags of 16x16x32). LDS stride 72 (2-way conflict = free).
// ---------------------------------------------------------------------------
template<int ACT, typename OutT>   // ACT: 0 none, 1 elu
__global__ __launch_bounds__(256) void mfma_gemm_kernel(
    const __hip_bfloat16* __restrict__ A,
    const __hip_bfloat16* __restrict__ BT,
    const float* __restrict__ bias,
    OutT* __restrict__ C,
    int M, int K, int N)
{
    constexpr int BM = 128, BN = 128, BK = 64, LDA = 72;
    __shared__ __align__(16) short As[BM * LDA];
    __shared__ __align__(16) short Bs[BN * LDA];

    const int tid  = threadIdx.x;
    const int lane = tid & 63;
    const int wid  = tid >> 6;
    const int wm   = wid >> 1;           // 0..1
    const int wn   = wid & 1;            // 0..1
    const int fr   = lane & 15;
    const int fk   = (lane >> 4) * 8;

    const int row0 = blockIdx.y * BM;
    const int col0 = blockIdx.x * BN;

    const short* Ag = (const short*)A;
    const short* Bg = (const short*)BT;

    f32x4 acc[4][4] = {};

    for (int k0 = 0; k0 < K; k0 += BK) {
        // stage A tile: 128 x 64 (1024 chunks of 8)
        #pragma unroll
        for (int it = 0; it < 4; ++it) {
            int chunk = it * 256 + tid;
            int r = chunk >> 3, c = chunk & 7;
            int gr = row0 + r;
            short8 v = {0, 0, 0, 0, 0, 0, 0, 0};
            if (gr < M) v = *(const short8*)(Ag + (size_t)gr * K + k0 + c * 8);
            *(short8*)(&As[r * LDA + c * 8]) = v;
        }
        // stage B^T tile: 128 x 64 (N multiple of 128)
        #pragma unroll
        for (int it = 0; it < 4; ++it) {
            int chunk = it * 256 + tid;
            int n = chunk >> 3, c = chunk & 7;
            short8 v = *(const short8*)(Bg + (size_t)(col0 + n) * K + k0 + c * 8);
            *(short8*)(&Bs[n * LDA + c * 8]) = v;
        }
        __syncthreads();
        #pragma unroll
        for (int kk = 0; kk < 2; ++kk) {
            short8 af[4], bf[4];
            #pragma unroll
            for (int i = 0; i < 4; ++i)
                af[i] = *(const short8*)(&As[(wm * 64 + i * 16 + fr) * LDA + kk * 32 + fk]);
            #pragma unroll
            for (int j = 0; j < 4; ++j)
                bf[j] = *(const short8*)(&Bs[(wn * 64 + j * 16 + fr) * LDA + kk * 32 + fk]);
            #pragma unroll
            for (int i = 0; i < 4; ++i)
                #pragma unroll
                for (int j = 0; j < 4; ++j)
                    acc[i][j] = __builtin_amdgcn_mfma_f32_16x16x32_bf16(af[i], bf[j], acc[i][j], 0, 0, 0);
        }
        __syncthreads();
    }

    // C/D layout: col = lane&15, row = (lane>>4)*4 + reg
    const int crow = row0 + wm * 64;
    const int ccol = col0 + wn * 64;
    #pragma unroll
    for (int i = 0; i < 4; ++i) {
        #pragma unroll
        for (int j = 0; j < 4; ++j) {
            int col = ccol + j * 16 + (lane & 15);
            float bv = bias ? bias[col] : 0.0f;
            #pragma unroll
            for (int reg = 0; reg < 4; ++reg) {
                int r = crow + i * 16 + (lane >> 4) * 4 + reg;
                if (r < M) {
                    float v = acc[i][j][reg] + bv;
                    if (ACT == 1) v = (v > 0.0f) ? v : expm1f(v);
                    C[(size_t)r * N + col] = (OutT)v;
                }
            }
        }
    }
}

// ---------------------------------------------------------------------------
// Fused GATv2 layer 1: one wave per dst node, CSR gather, online softmax.
// xl/xr bf16 [N,512] (separate tables; xl table is the only gathered one).
// out1 = elu(agg + b1) -> bf16 [N,512].
// Lane l owns channels [8l,8l+8); head = l/16; 16-lane-group reduce.
// lrelu(x) = max(x, 0.2x); exp2-domain softmax (log2e folded into att).
// ---------------------------------------------------------------------------
__global__ __launch_bounds__(256) void gatv2_l1_fused_kernel(
    const __hip_bfloat16* __restrict__ xl, const __hip_bfloat16* __restrict__ xr,
    const int* __restrict__ row, const int* __restrict__ src_sorted,
    const float* __restrict__ att, const float* __restrict__ b1,
    __hip_bfloat16* __restrict__ out1, int N)
{
    int d = blockIdx.x * 4 + (threadIdx.x >> 6);
    if (d >= N) return;
    int lane = threadIdx.x & 63;
    int cbase = lane * 8;
    const short* xlb = (const short*)xl;

    float xrd[8], attv[8];
    {
        uint4 raw = *reinterpret_cast<const uint4*>((const short*)xr + (size_t)d * HC1 + cbase);
        const unsigned* u = reinterpret_cast<const unsigned*>(&raw);
        #pragma unroll
        for (int j = 0; j < 4; ++j) {
            xrd[2 * j]     = __uint_as_float(u[j] << 16);
            xrd[2 * j + 1] = __uint_as_float(u[j] & 0xffff0000u);
        }
        #pragma unroll
        for (int k = 0; k < 8; ++k) attv[k] = att[cbase + k] * LOG2E;
    }

    float m = -__builtin_huge_valf();
    float s = 0.0f;
    float o[8] = {};

    int rs = row[d], re = row[d + 1];

    // prefetched gather: self-loop first, then CSR edges
    uint4 raw = *reinterpret_cast<const uint4*>(xlb + (size_t)d * HC1 + cbase);
    for (int it = rs - 1; it < re; ++it) {
        uint4 cur = raw;
        if (it + 1 < re) {
            int sn = src_sorted[it + 1];
            raw = *reinterpret_cast<const uint4*>(xlb + (size_t)sn * HC1 + cbase);
        }
        float v[8];
        const unsigned* u = reinterpret_cast<const unsigned*>(&cur);
        #pragma unroll
        for (int j = 0; j < 4; ++j) {
            v[2 * j]     = __uint_as_float(u[j] << 16);
            v[2 * j + 1] = __uint_as_float(u[j] & 0xffff0000u);
        }
        float t = 0.0f;
        #pragma unroll
        for (int k = 0; k < 8; ++k) {
            float ek = v[k] + xrd[k];
            float e = fmaxf(ek, NEG_SLOPE * ek);   // leaky_relu, 2 ops
            t = fmaf(e, attv[k], t);
        }
        t += __shfl_xor(t, 1);
        t += __shfl_xor(t, 2);
        t += __shfl_xor(t, 4);
        t += __shfl_xor(t, 8);
        // online softmax in exp2 domain (t is log2-scaled)
        if (t > m) {
            float r = exp2f(m - t);   // exp2(-inf)=0 on first edge
            s *= r;
            #pragma unroll
            for (int k = 0; k < 8; ++k) o[k] *= r;
            m = t;
        }
        float p = exp2f(t - m);
        s += p;
        #pragma unroll
        for (int k = 0; k < 8; ++k) o[k] = fmaf(p, v[k], o[k]);
    }

    float inv = 1.0f / (s + 1e-16f);
    short8 sv;
    #pragma unroll
    for (int k = 0; k < 8; ++k) {
        float val = o[k] * inv + b1[cbase + k];
        val = (val > 0.0f) ? val : expm1f(val);
        __hip_bfloat16 hb = __float2bfloat16(val);
        sv[k] = *reinterpret_cast<short*>(&hb);
    }
    *(short8*)((short*)out1 + (size_t)d * HC1 + cbase) = sv;
}

// ---------------------------------------------------------------------------
// Fused GATv2 layer 2 (H=1) + classifier + log_softmax: one wave per node.
// xl2/xr2 bf16 [N,128] separate. Lane l owns channels [2l,2l+2). Writes [N,2].
// ---------------------------------------------------------------------------
__global__ __launch_bounds__(256) void gatv2_l2_final_kernel(
    const __hip_bfloat16* __restrict__ xl2, const __hip_bfloat16* __restrict__ xr2,
    const int* __restrict__ row, const int* __restrict__ src_sorted,
    const float* __restrict__ att2, const float* __restrict__ b2,
    const float* __restrict__ w_out, const float* __restrict__ b_out,
    float* __restrict__ out, int N)
{
    int d = blockIdx.x * 4 + (threadIdx.x >> 6);
    if (d >= N) return;
    int lane = threadIdx.x & 63;
    int c0 = lane * 2;
    const short* xlb = (const short*)xl2;

    unsigned xr_raw = *reinterpret_cast<const unsigned*>((const short*)xr2 + (size_t)d * HID + c0);
    float xrd0 = __uint_as_float(xr_raw << 16);
    float xrd1 = __uint_as_float(xr_raw & 0xffff0000u);
    float a2x = att2[c0] * LOG2E;
    float a2y = att2[c0 + 1] * LOG2E;

    float m = -__builtin_huge_valf();
    float s = 0.0f;
    float o0 = 0.0f, o1 = 0.0f;

    int rs = row[d], re = row[d + 1];
    unsigned raw = *reinterpret_cast<const unsigned*>(xlb + (size_t)d * HID + c0);
    for (int it = rs - 1; it < re; ++it) {
        unsigned cur = raw;
        if (it + 1 < re) {
            int sn = src_sorted[it + 1];
            raw = *reinterpret_cast<const unsigned*>(xlb + (size_t)sn * HID + c0);
        }
        float v0 = __uint_as_float(cur << 16);
        float v1 = __uint_as_float(cur & 0xffff0000u);
        float e0 = v0 + xrd0; e0 = fmaxf(e0, NEG_SLOPE * e0);
        float e1 = v1 + xrd1; e1 = fmaxf(e1, NEG_SLOPE * e1);
        float t = fmaf(e0, a2x, e1 * a2y);
        #pragma unroll
        for (int off = 32; off; off >>= 1) t += __shfl_xor(t, off);
        if (t > m) {
            float r = exp2f(m - t);
            s *= r; o0 *= r; o1 *= r;
            m = t;
        }
        float p = exp2f(t - m);
        s += p;
        o0 = fmaf(p, v0, o0);
        o1 = fmaf(p, v1, o1);
    }

    float inv = 1.0f / (s + 1e-16f);
    float h0v = o0 * inv + b2[c0];
    float h1v = o1 * inv + b2[c0 + 1];
    h0v = (h0v > 0.0f) ? h0v : expm1f(h0v);
    h1v = (h1v > 0.0f) ? h1v : expm1f(h1v);

    float a0 = fmaf(h0v, w_out[c0 * 2 + 0], h1v * w_out[(c0 + 1) * 2 + 0]);
    float a1 = fmaf(h0v, w_out[c0 * 2 + 1], h1v * w_out[(c0 + 1) * 2 + 1]);
    #pragma unroll
    for (int off = 32; off; off >>= 1) {
        a0 += __shfl_xor(a0, off);
        a1 += __shfl_xor(a1, off);
    }
    if (lane == 0) {
        float z0 = a0 + b_out[0];
        float z1 = a1 + b_out[1];
        float mx = fmaxf(z0, z1);
        float lse = mx + logf(__expf(z0 - mx) + __expf(z1 - mx));
        out[(size_t)d * CLASSES + 0] = z0 - lse;
        out[(size_t)d * CLASSES + 1] = z1 - lse;
    }
}

// ---------------------------------------------------------------------------
// launch
// ---------------------------------------------------------------------------
extern "C" void kernel_launch(void* const* d_in, const int* in_sizes, int n_in,
                              void* d_out, int out_size, void* d_ws, size_t ws_size,
                              hipStream_t stream)
{
    const float* x     = (const float*)d_in[0];
    const int*   eidx  = (const int*)d_in[1];
    const float* w_in  = (const float*)d_in[2];
    const float* b_in  = (const float*)d_in[3];
    const float* wl1   = (const float*)d_in[4];
    const float* wr1   = (const float*)d_in[5];
    const float* att1  = (const float*)d_in[6];
    const float* b1    = (const float*)d_in[7];
    const float* wl2   = (const float*)d_in[8];
    const float* wr2   = (const float*)d_in[9];
    const float* att2  = (const float*)d_in[10];
    const float* b2    = (const float*)d_in[11];
    const float* w_out = (const float*)d_in[12];
    const float* b_out = (const float*)d_in[13];
    float* out = (float*)d_out;

    const int N = in_sizes[0] / F_IN;      // 50000
    const int E = in_sizes[1] / 2;         // 800000
    const int* src_arr = eidx;
    const int* dst_arr = eidx + E;

    // ---- workspace layout (peak ~183 MB) ----
    size_t off = 0;
    auto alloc = [&](size_t bytes) -> char* {
        char* ptr = (char*)d_ws + off;
        off += (bytes + 255) & ~(size_t)255;
        return ptr;
    };
    int* row        = (int*)alloc((size_t)(N + 1) * 4);
    int* cursor     = (int*)alloc((size_t)N * 4);
    int* deg        = (int*)alloc((size_t)N * 4);
    int* bsum       = (int*)alloc(64 * 4);
    int* src_sorted = (int*)alloc((size_t)E * 4);
    __hip_bfloat16* w_inT = (__hip_bfloat16*)alloc((size_t)F_IN * HID * 2);
    __hip_bfloat16* wT1l  = (__hip_bfloat16*)alloc((size_t)HID * HC1 * 2);
    __hip_bfloat16* wT1r  = (__hip_bfloat16*)alloc((size_t)HID * HC1 * 2);
    __hip_bfloat16* wT2l  = (__hip_bfloat16*)alloc((size_t)HC1 * HID * 2);
    __hip_bfloat16* wT2r  = (__hip_bfloat16*)alloc((size_t)HC1 * HID * 2);
    __hip_bfloat16* xb    = (__hip_bfloat16*)alloc((size_t)N * F_IN * 2);   // -> xl2
    __hip_bfloat16* h0b   = (__hip_bfloat16*)alloc((size_t)N * HID * 2);    // -> xr2
    __hip_bfloat16* xl1   = (__hip_bfloat16*)alloc((size_t)N * HC1 * 2);
    __hip_bfloat16* xr1   = (__hip_bfloat16*)alloc((size_t)N * HC1 * 2);
    __hip_bfloat16* out1  = (__hip_bfloat16*)alloc((size_t)N * HC1 * 2);

    __hip_bfloat16* xl2 = xb;    // xb dead after input GEMM
    __hip_bfloat16* xr2 = h0b;   // h0b dead after L1 GEMMs

    dim3 blk(256);
    const int NB_SCAN = (N + SCAN_CHUNK - 1) / SCAN_CHUNK;

    // ---- CSR build ----
    hipLaunchKernelGGL(zero_int_kernel, dim3(64), blk, 0, stream, deg, N);
    hipLaunchKernelGGL(deg_kernel, dim3((E + 255) / 256), blk, 0, stream, dst_arr, deg, E, N);
    hipLaunchKernelGGL(scan_partial_kernel, dim3(NB_SCAN), blk, 0, stream, deg, bsum, N);
    hipLaunchKernelGGL(scan_bsums_kernel, dim3(1), blk, 0, stream, bsum, NB_SCAN, row, N);
    hipLaunchKernelGGL(scan_final_kernel, dim3(NB_SCAN), blk, 0, stream, deg, bsum, row, cursor, N);
    hipLaunchKernelGGL(scatter_kernel, dim3((E + 255) / 256), blk, 0, stream,
                       src_arr, dst_arr, cursor, src_sorted, E, N);

    // ---- weight prep (single kernel) + x -> bf16 ----
    {
        int total = 128 * 128 + 4 * 128 * 512;
        hipLaunchKernelGGL(weights_prep_kernel, dim3((total + 255) / 256), blk, 0, stream,
                           w_in, wl1, wr1, wl2, wr2, w_inT, wT1l, wT1r, wT2l, wT2r);
        hipLaunchKernelGGL(f32_to_bf16_kernel, dim3(2048), blk, 0, stream, x, xb, N * F_IN);
    }
    // ---- input transform: MFMA + fused bias+elu -> bf16 ----
    {
        dim3 grid(HID / 128, (N + 127) / 128);
        hipLaunchKernelGGL((mfma_gemm_kernel<1, __hip_bfloat16>), grid, blk, 0, stream,
                           xb, w_inT, b_in, h0b, N, F_IN, HID);
    }
    // ---- layer 1 transforms (separate xl/xr tables) ----
    {
        dim3 grid(HC1 / 128, (N + 127) / 128);
        hipLaunchKernelGGL((mfma_gemm_kernel<0, __hip_bfloat16>), grid, blk, 0, stream,
                           h0b, wT1l, (const float*)nullptr, xl1, N, HID, HC1);
        hipLaunchKernelGGL((mfma_gemm_kernel<0, __hip_bfloat16>), grid, blk, 0, stream,
                           h0b, wT1r, (const float*)nullptr, xr1, N, HID, HC1);
    }
    // ---- fused layer 1 (gather + online softmax + bias + elu) -> bf16 ----
    {
        dim3 grid((N + 3) / 4);
        hipLaunchKernelGGL(gatv2_l1_fused_kernel, grid, blk, 0, stream,
                           xl1, xr1, row, src_sorted, att1, b1, out1, N);
    }
    // ---- layer 2 transforms ----
    {
        dim3 grid(HID / 128, (N + 127) / 128);
        hipLaunchKernelGGL((mfma_gemm_kernel<0, __hip_bfloat16>), grid, blk, 0, stream,
                           out1, wT2l, (const float*)nullptr, xl2, N, HC1, HID);
        hipLaunchKernelGGL((mfma_gemm_kernel<0, __hip_bfloat16>), grid, blk, 0, stream,
                           out1, wT2r, (const float*)nullptr, xr2, N, HC1, HID);
    }
    // ---- fused layer 2 + classifier + log_softmax -> d_out ----
    {
        dim3 grid((N + 3) / 4);
        hipLaunchKernelGGL(gatv2_l2_final_kernel, grid, blk, 0, stream,
                           xl2, xr2, row, src_sorted, att2, b2, w_out, b_out, out, N);
    }
}

// Round 9
// 578.451 us; speedup vs baseline: 5.3509x; 1.0172x over previous
//
#include <hip/hip_runtime.h>
#include <hip/hip_bf16.h>
#include <math.h>

// Problem constants (from reference)
#define F_IN   128
#define HID    128
#define HEADS  4
#define HC1    (HEADS*HID)   // 512
#define CLASSES 2
#define NEG_SLOPE 0.2f
#define LOG2E 1.44269504088896340736f
#define MNEG  -3.0e38f

#define SCAN_CHUNK 2048

typedef __attribute__((ext_vector_type(8))) short short8;
typedef __attribute__((ext_vector_type(4))) float f32x4;
typedef __attribute__((ext_vector_type(2))) float f32x2;

__device__ __forceinline__ f32x2 unpack2(unsigned u) {
    f32x2 r;
    r.x = __uint_as_float(u << 16);
    r.y = __uint_as_float(u & 0xffff0000u);
    return r;
}

// ---------------------------------------------------------------------------
// CSR build: deg histogram -> exclusive scan -> scatter src ids by dst
// ---------------------------------------------------------------------------
__global__ void zero_int_kernel(int* __restrict__ p, int n) {
    int i = blockIdx.x * blockDim.x + threadIdx.x;
    int stride = gridDim.x * blockDim.x;
    for (; i < n; i += stride) p[i] = 0;
}

__global__ void deg_kernel(const int* __restrict__ dst_arr, int* __restrict__ deg,
                           int E, int N) {
    int e = blockIdx.x * blockDim.x + threadIdx.x;
    if (e >= E) return;
    int d = dst_arr[e];
    if ((unsigned)d >= (unsigned)N) d = 0;
    atomicAdd(&deg[d], 1);
}

__global__ void scan_partial_kernel(const int* __restrict__ deg, int* __restrict__ bsum, int n) {
    __shared__ int sdata[256];
    int b = blockIdx.x, t = threadIdx.x;
    int base = b * SCAN_CHUNK;
    int s = 0;
    for (int i = t; i < SCAN_CHUNK; i += 256) {
        int idx = base + i;
        s += (idx < n) ? deg[idx] : 0;
    }
    sdata[t] = s;
    __syncthreads();
    for (int off = 128; off; off >>= 1) {
        if (t < off) sdata[t] += sdata[t + off];
        __syncthreads();
    }
    if (t == 0) bsum[b] = sdata[0];
}

__global__ void scan_bsums_kernel(int* __restrict__ bsum, int nb, int* __restrict__ row, int n) {
    if (blockIdx.x == 0 && threadIdx.x == 0) {
        int acc = 0;
        for (int i = 0; i < nb; ++i) { int v = bsum[i]; bsum[i] = acc; acc += v; }
        row[n] = acc;
    }
}

__global__ void scan_final_kernel(const int* __restrict__ deg, const int* __restrict__ bsum,
                                  int* __restrict__ row, int* __restrict__ cursor, int n) {
    __shared__ int tsum[256];
    int b = blockIdx.x, t = threadIdx.x;
    int base = b * SCAN_CHUNK + t * 8;
    int local[8];
    int s = 0;
    #pragma unroll
    for (int k = 0; k < 8; ++k) {
        int idx = base + k;
        int v = (idx < n) ? deg[idx] : 0;
        local[k] = s;
        s += v;
    }
    tsum[t] = s;
    __syncthreads();
    for (int off = 1; off < 256; off <<= 1) {
        int v = 0;
        if (t >= off) v = tsum[t - off];
        __syncthreads();
        if (t >= off) tsum[t] += v;
        __syncthreads();
    }
    int texcl = (t == 0) ? 0 : tsum[t - 1];
    int boff = bsum[b];
    #pragma unroll
    for (int k = 0; k < 8; ++k) {
        int idx = base + k;
        if (idx < n) {
            int v = boff + texcl + local[k];
            row[idx] = v;
            cursor[idx] = v;
        }
    }
}

__global__ void scatter_kernel(const int* __restrict__ src_arr, const int* __restrict__ dst_arr,
                               int* __restrict__ cursor, int* __restrict__ src_sorted,
                               int E, int N) {
    int e = blockIdx.x * blockDim.x + threadIdx.x;
    if (e >= E) return;
    int s = src_arr[e], d = dst_arr[e];
    if ((unsigned)s >= (unsigned)N) s = 0;
    if ((unsigned)d >= (unsigned)N) d = 0;
    int pos = atomicAdd(&cursor[d], 1);
    src_sorted[pos] = s;
}

// ---------------------------------------------------------------------------
// fused weight prep: transpose+bf16 all 5 weight matrices into combined
// layouts: w_inT [128][128]; wT1 [1024][128] (wl1|wr1); wT2 [256][512] (wl2|wr2)
// ---------------------------------------------------------------------------
__global__ void weights_prep_kernel(
    const float* __restrict__ w_in, const float* __restrict__ wl1,
    const float* __restrict__ wr1, const float* __restrict__ wl2,
    const float* __restrict__ wr2,
    __hip_bfloat16* __restrict__ w_inT, __hip_bfloat16* __restrict__ wT1,
    __hip_bfloat16* __restrict__ wT2)
{
    int t = blockIdx.x * blockDim.x + threadIdx.x;
    const int S0 = 128 * 128, S1 = 128 * 512;
    if (t < S0) {
        int n = t / 128, k = t % 128;
        w_inT[t] = __float2bfloat16(w_in[(size_t)k * 128 + n]);
    } else if (t < S0 + S1) {
        int idx = t - S0;              // wl1: K=128, N=512 -> wT1 rows 0..511
        int n = idx / 128, k = idx % 128;
        wT1[idx] = __float2bfloat16(wl1[(size_t)k * 512 + n]);
    } else if (t < S0 + 2 * S1) {
        int idx = t - S0 - S1;         // wr1 -> wT1 rows 512..1023
        int n = idx / 128, k = idx % 128;
        wT1[(size_t)(512 + n) * 128 + k] = __float2bfloat16(wr1[(size_t)k * 512 + n]);
    } else if (t < S0 + 3 * S1) {
        int idx = t - S0 - 2 * S1;     // wl2: K=512, N=128 -> wT2 rows 0..127
        int n = idx / 512, k = idx % 512;
        wT2[idx] = __float2bfloat16(wl2[(size_t)k * 128 + n]);
    } else if (t < S0 + 4 * S1) {
        int idx = t - S0 - 3 * S1;     // wr2 -> wT2 rows 128..255
        int n = idx / 512, k = idx % 512;
        wT2[(size_t)(128 + n) * 512 + k] = __float2bfloat16(wr2[(size_t)k * 128 + n]);
    }
}

// ---------------------------------------------------------------------------
// bf16 MFMA GEMM (128x128 tile): C = A @ BT^T (+bias, +elu)
// A: bf16 or f32 [M,K] (f32 converted during LDS staging), BT bf16 [N,K].
// BM=BN=128, BK=64; 4 waves, each 64x64 (4x4 frags of 16x16x32). LDS stride 72.
// ---------------------------------------------------------------------------
template<int ACT, typename AT, typename OutT>   // ACT: 0 none, 1 elu
__global__ __launch_bounds__(256) void mfma_gemm_kernel(
    const AT* __restrict__ A,
    const __hip_bfloat16* __restrict__ BT,
    const float* __restrict__ bias,
    OutT* __restrict__ C,
    int M, int K, int N)
{
    constexpr int BM = 128, BN = 128, BK = 64, LDA = 72;
    __shared__ __align__(16) short As[BM * LDA];
    __shared__ __align__(16) short Bs[BN * LDA];

    const int tid  = threadIdx.x;
    const int lane = tid & 63;
    const int wid  = tid >> 6;
    const int wm   = wid >> 1;
    const int wn   = wid & 1;
    const int fr   = lane & 15;
    const int fk   = (lane >> 4) * 8;

    const int row0 = blockIdx.y * BM;
    const int col0 = blockIdx.x * BN;

    const short* Bg = (const short*)BT;

    f32x4 acc[4][4] = {};

    for (int k0 = 0; k0 < K; k0 += BK) {
        // stage A tile: 128 x 64
        #pragma unroll
        for (int it = 0; it < 4; ++it) {
            int chunk = it * 256 + tid;
            int r = chunk >> 3, c = chunk & 7;
            int gr = row0 + r;
            short8 v = {0, 0, 0, 0, 0, 0, 0, 0};
            if (gr < M) {
                if constexpr (sizeof(AT) == 2) {
                    v = *(const short8*)((const short*)A + (size_t)gr * K + k0 + c * 8);
                } else {
                    const float* ap = (const float*)A + (size_t)gr * K + k0 + c * 8;
                    float4 a0 = *(const float4*)ap;
                    float4 a1 = *(const float4*)(ap + 4);
                    __hip_bfloat16 h;
                    h = __float2bfloat16(a0.x); v[0] = *(short*)&h;
                    h = __float2bfloat16(a0.y); v[1] = *(short*)&h;
                    h = __float2bfloat16(a0.z); v[2] = *(short*)&h;
                    h = __float2bfloat16(a0.w); v[3] = *(short*)&h;
                    h = __float2bfloat16(a1.x); v[4] = *(short*)&h;
                    h = __float2bfloat16(a1.y); v[5] = *(short*)&h;
                    h = __float2bfloat16(a1.z); v[6] = *(short*)&h;
                    h = __float2bfloat16(a1.w); v[7] = *(short*)&h;
                }
            }
            *(short8*)(&As[r * LDA + c * 8]) = v;
        }
        // stage B^T tile: 128 x 64 (N multiple of 128)
        #pragma unroll
        for (int it = 0; it < 4; ++it) {
            int chunk = it * 256 + tid;
            int n = chunk >> 3, c = chunk & 7;
            short8 v = *(const short8*)(Bg + (size_t)(col0 + n) * K + k0 + c * 8);
            *(short8*)(&Bs[n * LDA + c * 8]) = v;
        }
        __syncthreads();
        #pragma unroll
        for (int kk = 0; kk < 2; ++kk) {
            short8 af[4], bf[4];
            #pragma unroll
            for (int i = 0; i < 4; ++i)
                af[i] = *(const short8*)(&As[(wm * 64 + i * 16 + fr) * LDA + kk * 32 + fk]);
            #pragma unroll
            for (int j = 0; j < 4; ++j)
                bf[j] = *(const short8*)(&Bs[(wn * 64 + j * 16 + fr) * LDA + kk * 32 + fk]);
            #pragma unroll
            for (int i = 0; i < 4; ++i)
                #pragma unroll
                for (int j = 0; j < 4; ++j)
                    acc[i][j] = __builtin_amdgcn_mfma_f32_16x16x32_bf16(af[i], bf[j], acc[i][j], 0, 0, 0);
        }
        __syncthreads();
    }

    // C/D layout: col = lane&15, row = (lane>>4)*4 + reg
    const int crow = row0 + wm * 64;
    const int ccol = col0 + wn * 64;
    #pragma unroll
    for (int i = 0; i < 4; ++i) {
        #pragma unroll
        for (int j = 0; j < 4; ++j) {
            int col = ccol + j * 16 + (lane & 15);
            float bv = bias ? bias[col] : 0.0f;
            #pragma unroll
            for (int reg = 0; reg < 4; ++reg) {
                int r = crow + i * 16 + (lane >> 4) * 4 + reg;
                if (r < M) {
                    float v = acc[i][j][reg] + bv;
                    if (ACT == 1) v = (v > 0.0f) ? v : expm1f(v);
                    C[(size_t)r * N + col] = (OutT)v;
                }
            }
        }
    }
}

// ---------------------------------------------------------------------------
// Fused GATv2 layer 1: one wave per dst node, CSR gather, online softmax.
// xlr bf16 [N,1024]: cols 0..511 = xl (gathered), 512..1023 = xr.
// out1 = elu(agg + b1) -> bf16 [N,512].
// Lane l owns channels [8l,8l+8); head = l/16; 16-lane-group reduce.
// Inner loop on f32x2 (v_pk_*_f32); softmax in exp2 domain.
// ---------------------------------------------------------------------------
__global__ __launch_bounds__(256) void gatv2_l1_fused_kernel(
    const __hip_bfloat16* __restrict__ xlr,
    const int* __restrict__ row, const int* __restrict__ src_sorted,
    const float* __restrict__ att, const float* __restrict__ b1,
    __hip_bfloat16* __restrict__ out1, int N)
{
    int d = blockIdx.x * 4 + (threadIdx.x >> 6);
    if (d >= N) return;
    int lane = threadIdx.x & 63;
    int cbase = lane * 8;
    const short* basep = (const short*)xlr;

    f32x2 xrd2[4], attv2[4];
    {
        uint4 raw = *reinterpret_cast<const uint4*>(basep + (size_t)d * 1024 + 512 + cbase);
        const unsigned* u = reinterpret_cast<const unsigned*>(&raw);
        #pragma unroll
        for (int j = 0; j < 4; ++j) xrd2[j] = unpack2(u[j]);
        #pragma unroll
        for (int j = 0; j < 4; ++j) {
            attv2[j].x = att[cbase + 2 * j] * LOG2E;
            attv2[j].y = att[cbase + 2 * j + 1] * LOG2E;
        }
    }

    float m = MNEG;
    float s = 0.0f;
    f32x2 o2[4] = {};

    int rs = row[d], re = row[d + 1];

    // prefetched gather: self-loop first, then CSR edges
    uint4 raw = *reinterpret_cast<const uint4*>(basep + (size_t)d * 1024 + cbase);
    for (int it = rs - 1; it < re; ++it) {
        uint4 cur = raw;
        if (it + 1 < re) {
            int sn = src_sorted[it + 1];
            raw = *reinterpret_cast<const uint4*>(basep + (size_t)sn * 1024 + cbase);
        }
        const unsigned* u = reinterpret_cast<const unsigned*>(&cur);
        f32x2 v2[4];
        #pragma unroll
        for (int j = 0; j < 4; ++j) v2[j] = unpack2(u[j]);

        f32x2 tacc = {0.0f, 0.0f};
        #pragma unroll
        for (int j = 0; j < 4; ++j) {
            f32x2 e = v2[j] + xrd2[j];                      // v_pk_add
            f32x2 ne = e * NEG_SLOPE;                        // v_pk_mul
            e.x = fmaxf(e.x, ne.x);
            e.y = fmaxf(e.y, ne.y);
            tacc = __builtin_elementwise_fma(e, attv2[j], tacc);  // v_pk_fma
        }
        float t = tacc.x + tacc.y;
        t += __shfl_xor(t, 1);
        t += __shfl_xor(t, 2);
        t += __shfl_xor(t, 4);
        t += __shfl_xor(t, 8);
        if (t > m) {
            float r = exp2f(m - t);
            s *= r;
            f32x2 r2 = {r, r};
            #pragma unroll
            for (int j = 0; j < 4; ++j) o2[j] *= r2;
            m = t;
        }
        float p = exp2f(t - m);
        s += p;
        f32x2 p2 = {p, p};
        #pragma unroll
        for (int j = 0; j < 4; ++j) o2[j] = __builtin_elementwise_fma(p2, v2[j], o2[j]);
    }

    float inv = 1.0f / (s + 1e-16f);
    short8 sv;
    #pragma unroll
    for (int j = 0; j < 4; ++j) {
        #pragma unroll
        for (int h = 0; h < 2; ++h) {
            float val = ((h == 0) ? o2[j].x : o2[j].y) * inv + b1[cbase + 2 * j + h];
            val = (val > 0.0f) ? val : expm1f(val);
            __hip_bfloat16 hb = __float2bfloat16(val);
            sv[2 * j + h] = *reinterpret_cast<short*>(&hb);
        }
    }
    *(short8*)((short*)out1 + (size_t)d * HC1 + cbase) = sv;
}

// ---------------------------------------------------------------------------
// Fused GATv2 layer 2 (H=1) + classifier + log_softmax.
// xlr2 bf16 [N,256]: cols 0..127 = xl2, 128..255 = xr2.
// One wave per node, FOUR 16-lane groups each process every 4th edge with an
// independent online softmax; merged at the end via shfl_xor(16/32) rescale.
// Lane (g, gl): group g = lane>>4, gl = lane&15 owns channels [8gl, 8gl+8).
// ---------------------------------------------------------------------------
__global__ __launch_bounds__(256) void gatv2_l2_final_kernel(
    const __hip_bfloat16* __restrict__ xlr2,
    const int* __restrict__ row, const int* __restrict__ src_sorted,
    const float* __restrict__ att2, const float* __restrict__ b2,
    const float* __restrict__ w_out, const float* __restrict__ b_out,
    float* __restrict__ out, int N)
{
    int d = blockIdx.x * 4 + (threadIdx.x >> 6);
    if (d >= N) return;
    int lane = threadIdx.x & 63;
    int g  = lane >> 4;
    int gl = lane & 15;
    int cbase = gl * 8;
    const short* basep = (const short*)xlr2;

    f32x2 xrd2[4], attv2[4];
    {
        uint4 rawx = *reinterpret_cast<const uint4*>(basep + (size_t)d * 256 + 128 + cbase);
        const unsigned* u = reinterpret_cast<const unsigned*>(&rawx);
        #pragma unroll
        for (int j = 0; j < 4; ++j) xrd2[j] = unpack2(u[j]);
        #pragma unroll
        for (int j = 0; j < 4; ++j) {
            attv2[j].x = att2[cbase + 2 * j] * LOG2E;
            attv2[j].y = att2[cbase + 2 * j + 1] * LOG2E;
        }
    }

    float m = MNEG;
    float s = 0.0f;
    f32x2 o2[4] = {};

    int rs = row[d], re = row[d + 1];
    int L = re - rs + 1;   // virtual list: position 0 = self-loop, 1.. = CSR

    for (int p0 = g; p0 < L; p0 += 4) {
        int srcn = (p0 == 0) ? d : src_sorted[rs + p0 - 1];
        uint4 cur = *reinterpret_cast<const uint4*>(basep + (size_t)srcn * 256 + cbase);
        const unsigned* u = reinterpret_cast<const unsigned*>(&cur);
        f32x2 v2[4];
        #pragma unroll
        for (int j = 0; j < 4; ++j) v2[j] = unpack2(u[j]);

        f32x2 tacc = {0.0f, 0.0f};
        #pragma unroll
        for (int j = 0; j < 4; ++j) {
            f32x2 e = v2[j] + xrd2[j];
            f32x2 ne = e * NEG_SLOPE;
            e.x = fmaxf(e.x, ne.x);
            e.y = fmaxf(e.y, ne.y);
            tacc = __builtin_elementwise_fma(e, attv2[j], tacc);
        }
        float t = tacc.x + tacc.y;
        t += __shfl_xor(t, 1);
        t += __shfl_xor(t, 2);
        t += __shfl_xor(t, 4);
        t += __shfl_xor(t, 8);
        if (t > m) {
            float r = exp2f(m - t);
            s *= r;
            f32x2 r2 = {r, r};
            #pragma unroll
            for (int j = 0; j < 4; ++j) o2[j] *= r2;
            m = t;
        }
        float p = exp2f(t - m);
        s += p;
        f32x2 p2 = {p, p};
        #pragma unroll
        for (int j = 0; j < 4; ++j) o2[j] = __builtin_elementwise_fma(p2, v2[j], o2[j]);
    }

    // merge the 4 groups (lane^16, then lane^32); branchless (m init = -3e38)
    #pragma unroll
    for (int off = 16; off <= 32; off <<= 1) {
        float m_o = __shfl_xor(m, off);
        float s_o = __shfl_xor(s, off);
        f32x2 oo[4];
        #pragma unroll
        for (int j = 0; j < 4; ++j) {
            oo[j].x = __shfl_xor(o2[j].x, off);
            oo[j].y = __shfl_xor(o2[j].y, off);
        }
        float mn = fmaxf(m, m_o);
        float a = exp2f(m - mn);
        float b = exp2f(m_o - mn);
        s = s * a + s_o * b;
        f32x2 a2 = {a, a}, b2v = {b, b};
        #pragma unroll
        for (int j = 0; j < 4; ++j)
            o2[j] = o2[j] * a2 + oo[j] * b2v;
        m = mn;
    }

    // epilogue (all lanes hold merged state; groups redundant)
    float inv = 1.0f / (s + 1e-16f);
    float a0 = 0.0f, a1 = 0.0f;
    #pragma unroll
    for (int j = 0; j < 4; ++j) {
        #pragma unroll
        for (int h = 0; h < 2; ++h) {
            int c = cbase + 2 * j + h;
            float val = ((h == 0) ? o2[j].x : o2[j].y) * inv + b2[c];
            val = (val > 0.0f) ? val : expm1f(val);
            a0 = fmaf(val, w_out[c * 2 + 0], a0);
            a1 = fmaf(val, w_out[c * 2 + 1], a1);
        }
    }
    // reduce over the 16 lanes of the group
    #pragma unroll
    for (int off = 1; off <= 8; off <<= 1) {
        a0 += __shfl_xor(a0, off);
        a1 += __shfl_xor(a1, off);
    }
    if (lane == 0) {
        float z0 = a0 + b_out[0];
        float z1 = a1 + b_out[1];
        float mx = fmaxf(z0, z1);
        float lse = mx + logf(__expf(z0 - mx) + __expf(z1 - mx));
        out[(size_t)d * CLASSES + 0] = z0 - lse;
        out[(size_t)d * CLASSES + 1] = z1 - lse;
    }
}

// ---------------------------------------------------------------------------
// launch
// ---------------------------------------------------------------------------
extern "C" void kernel_launch(void* const* d_in, const int* in_sizes, int n_in,
                              void* d_out, int out_size, void* d_ws, size_t ws_size,
                              hipStream_t stream)
{
    const float* x     = (const float*)d_in[0];
    const int*   eidx  = (const int*)d_in[1];
    const float* w_in  = (const float*)d_in[2];
    const float* b_in  = (const float*)d_in[3];
    const float* wl1   = (const float*)d_in[4];
    const float* wr1   = (const float*)d_in[5];
    const float* att1  = (const float*)d_in[6];
    const float* b1    = (const float*)d_in[7];
    const float* wl2   = (const float*)d_in[8];
    const float* wr2   = (const float*)d_in[9];
    const float* att2  = (const float*)d_in[10];
    const float* b2    = (const float*)d_in[11];
    const float* w_out = (const float*)d_in[12];
    const float* b_out = (const float*)d_in[13];
    float* out = (float*)d_out;

    const int N = in_sizes[0] / F_IN;      // 50000
    const int E = in_sizes[1] / 2;         // 800000
    const int* src_arr = eidx;
    const int* dst_arr = eidx + E;

    // ---- workspace layout (peak ~172 MB) ----
    size_t off = 0;
    auto alloc = [&](size_t bytes) -> char* {
        char* ptr = (char*)d_ws + off;
        off += (bytes + 255) & ~(size_t)255;
        return ptr;
    };
    int* row        = (int*)alloc((size_t)(N + 1) * 4);
    int* cursor     = (int*)alloc((size_t)N * 4);
    int* deg        = (int*)alloc((size_t)N * 4);
    int* bsum       = (int*)alloc(64 * 4);
    int* src_sorted = (int*)alloc((size_t)E * 4);
    __hip_bfloat16* w_inT = (__hip_bfloat16*)alloc((size_t)F_IN * HID * 2);
    __hip_bfloat16* wT1   = (__hip_bfloat16*)alloc((size_t)2 * HC1 * HID * 2);  // [1024][128]
    __hip_bfloat16* wT2   = (__hip_bfloat16*)alloc((size_t)2 * HID * HC1 * 2);  // [256][512]
    __hip_bfloat16* h0b   = (__hip_bfloat16*)alloc((size_t)N * HID * 2);
    __hip_bfloat16* xlr1  = (__hip_bfloat16*)alloc((size_t)N * 2 * HC1 * 2);    // [N][1024]
    __hip_bfloat16* out1  = (__hip_bfloat16*)alloc((size_t)N * HC1 * 2);

    __hip_bfloat16* xlr2 = xlr1;   // [N][256] overlays xlr1 (dead after fused L1)

    dim3 blk(256);
    const int NB_SCAN = (N + SCAN_CHUNK - 1) / SCAN_CHUNK;

    // ---- CSR build ----
    hipLaunchKernelGGL(zero_int_kernel, dim3(64), blk, 0, stream, deg, N);
    hipLaunchKernelGGL(deg_kernel, dim3((E + 255) / 256), blk, 0, stream, dst_arr, deg, E, N);
    hipLaunchKernelGGL(scan_partial_kernel, dim3(NB_SCAN), blk, 0, stream, deg, bsum, N);
    hipLaunchKernelGGL(scan_bsums_kernel, dim3(1), blk, 0, stream, bsum, NB_SCAN, row, N);
    hipLaunchKernelGGL(scan_final_kernel, dim3(NB_SCAN), blk, 0, stream, deg, bsum, row, cursor, N);
    hipLaunchKernelGGL(scatter_kernel, dim3((E + 255) / 256), blk, 0, stream,
                       src_arr, dst_arr, cursor, src_sorted, E, N);

    // ---- weight prep (single kernel, combined layouts) ----
    {
        int total = 128 * 128 + 4 * 128 * 512;
        hipLaunchKernelGGL(weights_prep_kernel, dim3((total + 255) / 256), blk, 0, stream,
                           w_in, wl1, wr1, wl2, wr2, w_inT, wT1, wT2);
    }
    // ---- input transform: MFMA (f32 A staged->bf16) + fused bias+elu ----
    {
        dim3 grid(HID / 128, (N + 127) / 128);
        hipLaunchKernelGGL((mfma_gemm_kernel<1, float, __hip_bfloat16>), grid, blk, 0, stream,
                           x, w_inT, b_in, h0b, N, F_IN, HID);
    }
    // ---- layer 1 transforms: ONE combined MFMA GEMM -> xlr1 [N][1024] ----
    {
        dim3 grid(2 * HC1 / 128, (N + 127) / 128);
        hipLaunchKernelGGL((mfma_gemm_kernel<0, __hip_bfloat16, __hip_bfloat16>), grid, blk, 0, stream,
                           h0b, wT1, (const float*)nullptr, xlr1, N, HID, 2 * HC1);
    }
    // ---- fused layer 1 (gather + online softmax + bias + elu) -> bf16 ----
    {
        dim3 grid((N + 3) / 4);
        hipLaunchKernelGGL(gatv2_l1_fused_kernel, grid, blk, 0, stream,
                           xlr1, row, src_sorted, att1, b1, out1, N);
    }
    // ---- layer 2 transforms: ONE combined MFMA GEMM -> xlr2 [N][256] ----
    {
        dim3 grid(2 * HID / 128, (N + 127) / 128);
        hipLaunchKernelGGL((mfma_gemm_kernel<0, __hip_bfloat16, __hip_bfloat16>), grid, blk, 0, stream,
                           out1, wT2, (const float*)nullptr, xlr2, N, HC1, 2 * HID);
    }
    // ---- fused layer 2 + classifier + log_softmax -> d_out ----
    {
        dim3 grid((N + 3) / 4);
        hipLaunchKernelGGL(gatv2_l2_final_kernel, grid, blk, 0, stream,
                           xlr2, row, src_sorted, att2, b2, w_out, b_out, out, N);
    }
}